// Round 1
// baseline (574.614 us; speedup 1.0000x reference)
//
#include <hip/hip_runtime.h>
#include <cmath>

#define B_ 512
#define N_ 1024
#define M_ 64
#define H_ 512
#define NH_ 4
#define EPS_ 1e-8f

__device__ __forceinline__ float sigmoidf_(float x) { return 1.f / (1.f + expf(-x)); }
__device__ __forceinline__ float softplusf_(float x) { return x > 20.f ? x : log1pf(expf(x)); }

// ---------------- prep: x2 = [in_data | prev_reads(b-major) | h0], Wcat = [W_ih | W_hh]
__global__ void k_prep_x2(const float* __restrict__ in_data,
                          const float* __restrict__ prev_reads,
                          const float* __restrict__ h0,
                          float* __restrict__ x2) {
  const int b = blockIdx.x;
  for (int j = threadIdx.x; j < 1024; j += blockDim.x) {
    float v;
    if (j < 256) v = in_data[(size_t)b * 256 + j];
    else if (j < 512) { int jj = j - 256; v = prev_reads[(size_t)(jj >> 6) * B_ * 64 + (size_t)b * 64 + (jj & 63)]; }
    else v = h0[(size_t)b * H_ + (j - 512)];
    x2[(size_t)b * 1024 + j] = v;
  }
}

__global__ void k_prep_w(const float* __restrict__ W_ih, const float* __restrict__ W_hh,
                         const float* __restrict__ b_ih, const float* __restrict__ b_hh,
                         float* __restrict__ Wcat, float* __restrict__ bcat) {
  const int j = blockIdx.x;  // 0..2047
  for (int k = threadIdx.x; k < 1024; k += blockDim.x)
    Wcat[(size_t)j * 1024 + k] = (k < 512) ? W_ih[(size_t)j * 512 + k] : W_hh[(size_t)j * 512 + (k - 512)];
  if (threadIdx.x == 0) bcat[j] = b_ih[j] + b_hh[j];
}

// ---------------- generic f32 GEMM: C[M,N] = A[M,K] * W[N,K]^T + bias, optional sigmoid
// M multiple of 64, K multiple of 16, N arbitrary (bounds-checked)
template <bool SIG>
__global__ __launch_bounds__(256) void k_gemm(const float* __restrict__ A,
                                              const float* __restrict__ W,
                                              const float* __restrict__ bias,
                                              float* __restrict__ C,
                                              int Nn, int Kk, int ldc) {
  __shared__ float As[16][68];
  __shared__ float Bs[16][68];
  const int tid = threadIdx.x;
  const int tx = tid & 15, ty = tid >> 4;
  const int m0 = blockIdx.y * 64, n0 = blockIdx.x * 64;
  const int lr = tid >> 2, lc = (tid & 3) << 2;
  float acc[4][4] = {};
  for (int k0 = 0; k0 < Kk; k0 += 16) {
    float4 av = *(const float4*)&A[(size_t)(m0 + lr) * Kk + k0 + lc];
    float4 wv = make_float4(0.f, 0.f, 0.f, 0.f);
    if (n0 + lr < Nn) wv = *(const float4*)&W[(size_t)(n0 + lr) * Kk + k0 + lc];
    As[lc + 0][lr] = av.x; As[lc + 1][lr] = av.y; As[lc + 2][lr] = av.z; As[lc + 3][lr] = av.w;
    Bs[lc + 0][lr] = wv.x; Bs[lc + 1][lr] = wv.y; Bs[lc + 2][lr] = wv.z; Bs[lc + 3][lr] = wv.w;
    __syncthreads();
#pragma unroll
    for (int kk = 0; kk < 16; ++kk) {
      float a_[4], b_[4];
#pragma unroll
      for (int i = 0; i < 4; ++i) { a_[i] = As[kk][ty * 4 + i]; b_[i] = Bs[kk][tx * 4 + i]; }
#pragma unroll
      for (int i = 0; i < 4; ++i)
#pragma unroll
        for (int j = 0; j < 4; ++j) acc[i][j] = fmaf(a_[i], b_[j], acc[i][j]);
    }
    __syncthreads();
  }
#pragma unroll
  for (int i = 0; i < 4; ++i) {
    const int m = m0 + ty * 4 + i;
#pragma unroll
    for (int j = 0; j < 4; ++j) {
      const int n = n0 + tx * 4 + j;
      if (n < Nn) {
        float v = acc[i][j] + bias[n];
        if (SIG) v = 1.f / (1.f + expf(-v));
        C[(size_t)m * ldc + n] = v;
      }
    }
  }
}

// ---------------- LSTM pointwise
__global__ void k_lstm(const float* __restrict__ gates, const float* __restrict__ c0,
                       float* __restrict__ h) {
  const int idx = blockIdx.x * blockDim.x + threadIdx.x;  // < 512*512
  const int b = idx >> 9, j = idx & 511;
  const float* g = gates + (size_t)b * 2048;
  const float ig = g[j], fg = g[512 + j], gg = g[1024 + j], og = g[1536 + j];
  const float c = sigmoidf_(fg) * c0[idx] + sigmoidf_(ig) * tanhf(gg);
  h[idx] = sigmoidf_(og) * tanhf(c);
}

// ---------------- per-head params: normalized keys, (beta,g,sh,gamma), erase/add
// unit = type*2048 + head*512 + b ; one wave per unit
__global__ void k_params(const float* __restrict__ P, float* __restrict__ kn,
                         float* __restrict__ par, float* __restrict__ ea) {
  const int unit = blockIdx.x;
  const int type = unit >> 11;
  const int rem = unit & 2047;
  const int head = rem >> 9;
  const int b = rem & 511;
  const int lane = threadIdx.x;  // 64
  const float* p = P + (size_t)b * 1072 + (type == 0 ? head * 70 : 280 + head * 198);
  const float kv = tanhf(p[lane]);
  float ss = kv * kv;
#pragma unroll
  for (int off = 32; off > 0; off >>= 1) ss += __shfl_xor(ss, off);
  kn[(size_t)unit * 64 + lane] = kv / (sqrtf(ss) + EPS_);
  if (lane == 0) {
    float* pp = par + (size_t)unit * 8;
    pp[0] = softplusf_(p[64]);
    pp[1] = sigmoidf_(p[65]);
    const float s0 = p[66], s1 = p[67], s2 = p[68];
    const float mx = fmaxf(s0, fmaxf(s1, s2));
    const float e0 = expf(s0 - mx), e1 = expf(s1 - mx), e2 = expf(s2 - mx);
    const float inv = 1.f / (e0 + e1 + e2);
    pp[2] = e0 * inv; pp[3] = e1 * inv; pp[4] = e2 * inv;
    pp[5] = 1.f + softplusf_(p[69]);
  }
  if (type == 1) {
    ea[((size_t)head * 512 + b) * 128 + lane] = sigmoidf_(p[70 + lane]);
    ea[((size_t)head * 512 + b) * 128 + 64 + lane] = tanhf(p[134 + lane]);
  }
}

// ---------------- streaming pass over memory: apply updates j<pass in registers,
// emit cosine scores for head `pass` (if <4), accumulate reads for head pass-1.
__global__ __launch_bounds__(256) void k_score(const float* __restrict__ mem0,
                                               const float* __restrict__ kn,
                                               const float* __restrict__ ea,
                                               const float* __restrict__ wbuf,
                                               float* __restrict__ sbuf,
                                               float* __restrict__ reads,
                                               int pass) {
  const int b = blockIdx.x;
  const int tid = threadIdx.x;
  const int grp = tid >> 4, m4 = tid & 15;
  const int ms = m4 * 4;
  __shared__ float knr_s[64], knw_s[64];
  __shared__ float e_s[4][64], a_s[4][64];
  __shared__ float red[256][4];
  if (pass < 4 && tid < 64) {
    knr_s[tid] = kn[((size_t)(0 * 4 + pass) * 512 + b) * 64 + tid];
    knw_s[tid] = kn[((size_t)(1 * 4 + pass) * 512 + b) * 64 + tid];
  }
  if (tid < 64) {
    for (int j = 0; j < pass; ++j) {
      e_s[j][tid] = ea[((size_t)j * 512 + b) * 128 + tid];
      a_s[j][tid] = ea[((size_t)j * 512 + b) * 128 + 64 + tid];
    }
  }
  __syncthreads();
  float r0 = 0.f, r1 = 0.f, r2 = 0.f, r3 = 0.f;
  for (int it = 0; it < 64; ++it) {
    const int n = it * 16 + grp;
    const float4 v0 = *(const float4*)&mem0[((size_t)b * 1024 + n) * 64 + ms];
    float vx = v0.x, vy = v0.y, vz = v0.z, vw = v0.w;
    for (int j = 0; j < pass; ++j) {
      const float ww = wbuf[((size_t)(4 + j) * 512 + b) * 1024 + n];
      if (j == pass - 1) {
        const float wr = wbuf[((size_t)j * 512 + b) * 1024 + n];
        r0 = fmaf(wr, vx, r0); r1 = fmaf(wr, vy, r1);
        r2 = fmaf(wr, vz, r2); r3 = fmaf(wr, vw, r3);
      }
      vx = vx * (1.f - ww * e_s[j][ms + 0]) + ww * a_s[j][ms + 0];
      vy = vy * (1.f - ww * e_s[j][ms + 1]) + ww * a_s[j][ms + 1];
      vz = vz * (1.f - ww * e_s[j][ms + 2]) + ww * a_s[j][ms + 2];
      vw = vw * (1.f - ww * e_s[j][ms + 3]) + ww * a_s[j][ms + 3];
    }
    if (pass < 4) {
      float ssq = vx * vx + vy * vy + vz * vz + vw * vw;
      float dr = vx * knr_s[ms] + vy * knr_s[ms + 1] + vz * knr_s[ms + 2] + vw * knr_s[ms + 3];
      float dw = vx * knw_s[ms] + vy * knw_s[ms + 1] + vz * knw_s[ms + 2] + vw * knw_s[ms + 3];
#pragma unroll
      for (int off = 1; off < 16; off <<= 1) {
        ssq += __shfl_xor(ssq, off);
        dr += __shfl_xor(dr, off);
        dw += __shfl_xor(dw, off);
      }
      if (m4 == 0) {
        const float inv = 1.f / (sqrtf(ssq) + EPS_);
        sbuf[((size_t)0 * 512 + b) * 1024 + n] = dr * inv;
        sbuf[((size_t)1 * 512 + b) * 1024 + n] = dw * inv;
      }
    }
  }
  if (pass >= 1) {
    red[tid][0] = r0; red[tid][1] = r1; red[tid][2] = r2; red[tid][3] = r3;
    __syncthreads();
    if (tid < 16) {
      float s0 = 0.f, s1 = 0.f, s2 = 0.f, s3 = 0.f;
      for (int g2 = 0; g2 < 16; ++g2) {
        s0 += red[g2 * 16 + tid][0]; s1 += red[g2 * 16 + tid][1];
        s2 += red[g2 * 16 + tid][2]; s3 += red[g2 * 16 + tid][3];
      }
      float* rp = &reads[((size_t)(pass - 1) * 512 + b) * 64 + tid * 4];
      rp[0] = s0; rp[1] = s1; rp[2] = s2; rp[3] = s3;
    }
  }
}

// ---------------- softmax + gate + shift + sharpen -> final weights
__global__ void k_finalize(const float* __restrict__ sbuf, const float* __restrict__ par,
                           const float* __restrict__ prev_w_r, const float* __restrict__ prev_w_w,
                           float* __restrict__ wbuf, int head) {
  const int b = blockIdx.x;
  const int type = blockIdx.y;
  const int tid = threadIdx.x;  // 256
  __shared__ float wg_s[1024];
  __shared__ float red_s[4];
  const float* pp = &par[((size_t)(type * 4 + head) * 512 + b) * 8];
  const float beta = pp[0], g = pp[1], sh0 = pp[2], sh1 = pp[3], sh2 = pp[4], gamma = pp[5];
  const float* srow = &sbuf[((size_t)type * 512 + b) * 1024];
  const float* prevw = ((type == 0) ? prev_w_r : prev_w_w) + ((size_t)head * 512 + b) * 1024;

  float z[4];
  float lmax = -1e30f;
#pragma unroll
  for (int k2 = 0; k2 < 4; ++k2) { z[k2] = beta * srow[tid + k2 * 256]; lmax = fmaxf(lmax, z[k2]); }
#pragma unroll
  for (int off = 32; off > 0; off >>= 1) lmax = fmaxf(lmax, __shfl_xor(lmax, off));
  if ((tid & 63) == 0) red_s[tid >> 6] = lmax;
  __syncthreads();
  const float gmax = fmaxf(fmaxf(red_s[0], red_s[1]), fmaxf(red_s[2], red_s[3]));
  __syncthreads();
  float ez[4]; float lsum = 0.f;
#pragma unroll
  for (int k2 = 0; k2 < 4; ++k2) { ez[k2] = expf(z[k2] - gmax); lsum += ez[k2]; }
#pragma unroll
  for (int off = 32; off > 0; off >>= 1) lsum += __shfl_xor(lsum, off);
  if ((tid & 63) == 0) red_s[tid >> 6] = lsum;
  __syncthreads();
  const float gsum = red_s[0] + red_s[1] + red_s[2] + red_s[3];
  const float invs = 1.f / gsum;
#pragma unroll
  for (int k2 = 0; k2 < 4; ++k2) {
    const int n = tid + k2 * 256;
    const float wc = ez[k2] * invs;
    wg_s[n] = g * wc + (1.f - g) * prevw[n];
  }
  __syncthreads();
  float wp[4]; float lsum2 = 0.f;
#pragma unroll
  for (int k2 = 0; k2 < 4; ++k2) {
    const int n = tid + k2 * 256;
    const float wsv = sh0 * wg_s[(n + 1023) & 1023] + sh1 * wg_s[n] + sh2 * wg_s[(n + 1) & 1023];
    wp[k2] = powf(wsv, gamma);
    lsum2 += wp[k2];
  }
#pragma unroll
  for (int off = 32; off > 0; off >>= 1) lsum2 += __shfl_xor(lsum2, off);
  if ((tid & 63) == 0) red_s[tid >> 6] = lsum2;
  __syncthreads();
  const float gsum2 = red_s[0] + red_s[1] + red_s[2] + red_s[3];
  const float inv2 = 1.f / (gsum2 + EPS_);
  float* wrow = &wbuf[((size_t)(type * 4 + head) * 512 + b) * 1024];
#pragma unroll
  for (int k2 = 0; k2 < 4; ++k2) wrow[tid + k2 * 256] = wp[k2] * inv2;
}

// ---------------- concat(h, reads)
__global__ void k_aout(const float* __restrict__ h, const float* __restrict__ reads,
                       float* __restrict__ Aout) {
  const int b = blockIdx.x;
  for (int j = threadIdx.x; j < 768; j += blockDim.x) {
    float v;
    if (j < 512) v = h[(size_t)b * 512 + j];
    else { int jj = j - 512; v = reads[((size_t)(jj >> 6) * 512 + b) * 64 + (jj & 63)]; }
    Aout[(size_t)b * 768 + j] = v;
  }
}

extern "C" void kernel_launch(void* const* d_in, const int* in_sizes, int n_in,
                              void* d_out, int out_size, void* d_ws, size_t ws_size,
                              hipStream_t stream) {
  (void)in_sizes; (void)n_in; (void)out_size; (void)ws_size;
  const float* in_data = (const float*)d_in[0];
  const float* memory = (const float*)d_in[1];
  const float* prev_reads = (const float*)d_in[2];
  const float* prev_w_r = (const float*)d_in[3];
  const float* prev_w_w = (const float*)d_in[4];
  const float* h0 = (const float*)d_in[5];
  const float* c0 = (const float*)d_in[6];
  const float* W_ih = (const float*)d_in[7];
  const float* b_ih = (const float*)d_in[8];
  const float* W_hh = (const float*)d_in[9];
  const float* b_hh = (const float*)d_in[10];
  const float* W_rh = (const float*)d_in[11];
  const float* b_rh = (const float*)d_in[12];
  const float* W_wh = (const float*)d_in[13];
  const float* b_wh = (const float*)d_in[14];
  const float* W_out = (const float*)d_in[15];
  const float* b_out = (const float*)d_in[16];
  float* out = (float*)d_out;

  float* ws = (float*)d_ws;
  float* x2 = ws;    ws += (size_t)512 * 1024;
  float* Wcat = ws;  ws += (size_t)2048 * 1024;
  float* bcat = ws;  ws += 2048;
  float* gates = ws; ws += (size_t)512 * 2048;
  float* h = ws;     ws += (size_t)512 * 512;
  float* P = ws;     ws += (size_t)512 * 1072;
  float* kn = ws;    ws += (size_t)2 * 4 * 512 * 64;
  float* par = ws;   ws += (size_t)2 * 4 * 512 * 8;
  float* ea = ws;    ws += (size_t)4 * 512 * 128;
  float* sbuf = ws;  ws += (size_t)2 * 512 * 1024;
  float* wbuf = ws;  ws += (size_t)2 * 4 * 512 * 1024;
  float* reads = ws; ws += (size_t)4 * 512 * 64;
  float* Aout = ws;  ws += (size_t)512 * 768;

  k_prep_x2<<<512, 256, 0, stream>>>(in_data, prev_reads, h0, x2);
  k_prep_w<<<2048, 256, 0, stream>>>(W_ih, W_hh, b_ih, b_hh, Wcat, bcat);
  k_gemm<false><<<dim3(2048 / 64, 512 / 64), 256, 0, stream>>>(x2, Wcat, bcat, gates, 2048, 1024, 2048);
  k_lstm<<<512 * 512 / 256, 256, 0, stream>>>(gates, c0, h);
  k_gemm<false><<<dim3((280 + 63) / 64, 8), 256, 0, stream>>>(h, W_rh, b_rh, P, 280, 512, 1072);
  k_gemm<false><<<dim3((792 + 63) / 64, 8), 256, 0, stream>>>(h, W_wh, b_wh, P + 280, 792, 512, 1072);
  k_params<<<4096, 64, 0, stream>>>(P, kn, par, ea);
  for (int i = 0; i < 4; ++i) {
    k_score<<<512, 256, 0, stream>>>(memory, kn, ea, wbuf, sbuf, reads, i);
    k_finalize<<<dim3(512, 2), 256, 0, stream>>>(sbuf, par, prev_w_r, prev_w_w, wbuf, i);
  }
  k_score<<<512, 256, 0, stream>>>(memory, kn, ea, wbuf, sbuf, reads, 4);
  k_aout<<<512, 256, 0, stream>>>(h, reads, Aout);
  k_gemm<true><<<dim3(256 / 64, 8), 256, 0, stream>>>(Aout, W_out, b_out, out, 256, 768, 256);
}

// Round 2
// 351.570 us; speedup vs baseline: 1.6344x; 1.6344x over previous
//
#include <hip/hip_runtime.h>
#include <cmath>

#define B_ 512
#define N_ 1024
#define M_ 64
#define H_ 512
#define NH_ 4
#define EPS_ 1e-8f
#define CH_ 16  // n-chunks per batch row in k_score

__device__ __forceinline__ float sigmoidf_(float x) { return 1.f / (1.f + expf(-x)); }
__device__ __forceinline__ float softplusf_(float x) { return x > 20.f ? x : log1pf(expf(x)); }

// ---------------- prep: x2 = [in_data | prev_reads(b-major) | h0], Wcat = [W_ih | W_hh]
__global__ void k_prep_x2(const float* __restrict__ in_data,
                          const float* __restrict__ prev_reads,
                          const float* __restrict__ h0,
                          float* __restrict__ x2) {
  const int b = blockIdx.x;
  for (int j = threadIdx.x; j < 1024; j += blockDim.x) {
    float v;
    if (j < 256) v = in_data[(size_t)b * 256 + j];
    else if (j < 512) { int jj = j - 256; v = prev_reads[(size_t)(jj >> 6) * B_ * 64 + (size_t)b * 64 + (jj & 63)]; }
    else v = h0[(size_t)b * H_ + (j - 512)];
    x2[(size_t)b * 1024 + j] = v;
  }
}

__global__ void k_prep_w(const float* __restrict__ W_ih, const float* __restrict__ W_hh,
                         const float* __restrict__ b_ih, const float* __restrict__ b_hh,
                         float* __restrict__ Wcat, float* __restrict__ bcat) {
  const int j = blockIdx.x;  // 0..2047
  for (int k = threadIdx.x; k < 1024; k += blockDim.x)
    Wcat[(size_t)j * 1024 + k] = (k < 512) ? W_ih[(size_t)j * 512 + k] : W_hh[(size_t)j * 512 + (k - 512)];
  if (threadIdx.x == 0) bcat[j] = b_ih[j] + b_hh[j];
}

// ---------------- generic f32 GEMM: C[M,N] = A[M,K] * W[N,K]^T + bias, optional sigmoid
template <bool SIG>
__global__ __launch_bounds__(256) void k_gemm(const float* __restrict__ A,
                                              const float* __restrict__ W,
                                              const float* __restrict__ bias,
                                              float* __restrict__ C,
                                              int Nn, int Kk, int ldc) {
  __shared__ float As[16][68];
  __shared__ float Bs[16][68];
  const int tid = threadIdx.x;
  const int tx = tid & 15, ty = tid >> 4;
  const int m0 = blockIdx.y * 64, n0 = blockIdx.x * 64;
  const int lr = tid >> 2, lc = (tid & 3) << 2;
  float acc[4][4] = {};
  for (int k0 = 0; k0 < Kk; k0 += 16) {
    float4 av = *(const float4*)&A[(size_t)(m0 + lr) * Kk + k0 + lc];
    float4 wv = make_float4(0.f, 0.f, 0.f, 0.f);
    if (n0 + lr < Nn) wv = *(const float4*)&W[(size_t)(n0 + lr) * Kk + k0 + lc];
    As[lc + 0][lr] = av.x; As[lc + 1][lr] = av.y; As[lc + 2][lr] = av.z; As[lc + 3][lr] = av.w;
    Bs[lc + 0][lr] = wv.x; Bs[lc + 1][lr] = wv.y; Bs[lc + 2][lr] = wv.z; Bs[lc + 3][lr] = wv.w;
    __syncthreads();
#pragma unroll
    for (int kk = 0; kk < 16; ++kk) {
      float a_[4], b_[4];
#pragma unroll
      for (int i = 0; i < 4; ++i) { a_[i] = As[kk][ty * 4 + i]; b_[i] = Bs[kk][tx * 4 + i]; }
#pragma unroll
      for (int i = 0; i < 4; ++i)
#pragma unroll
        for (int j = 0; j < 4; ++j) acc[i][j] = fmaf(a_[i], b_[j], acc[i][j]);
    }
    __syncthreads();
  }
#pragma unroll
  for (int i = 0; i < 4; ++i) {
    const int m = m0 + ty * 4 + i;
#pragma unroll
    for (int j = 0; j < 4; ++j) {
      const int n = n0 + tx * 4 + j;
      if (n < Nn) {
        float v = acc[i][j] + bias[n];
        if (SIG) v = 1.f / (1.f + expf(-v));
        C[(size_t)m * ldc + n] = v;
      }
    }
  }
}

// ---------------- LSTM pointwise
__global__ void k_lstm(const float* __restrict__ gates, const float* __restrict__ c0,
                       float* __restrict__ h) {
  const int idx = blockIdx.x * blockDim.x + threadIdx.x;  // < 512*512
  const int b = idx >> 9, j = idx & 511;
  const float* g = gates + (size_t)b * 2048;
  const float ig = g[j], fg = g[512 + j], gg = g[1024 + j], og = g[1536 + j];
  const float c = sigmoidf_(fg) * c0[idx] + sigmoidf_(ig) * tanhf(gg);
  h[idx] = sigmoidf_(og) * tanhf(c);
}

// ---------------- per-head params
__global__ void k_params(const float* __restrict__ P, float* __restrict__ kn,
                         float* __restrict__ par, float* __restrict__ ea) {
  const int unit = blockIdx.x;
  const int type = unit >> 11;
  const int rem = unit & 2047;
  const int head = rem >> 9;
  const int b = rem & 511;
  const int lane = threadIdx.x;  // 64
  const float* p = P + (size_t)b * 1072 + (type == 0 ? head * 70 : 280 + head * 198);
  const float kv = tanhf(p[lane]);
  float ss = kv * kv;
#pragma unroll
  for (int off = 32; off > 0; off >>= 1) ss += __shfl_xor(ss, off);
  kn[(size_t)unit * 64 + lane] = kv / (sqrtf(ss) + EPS_);
  if (lane == 0) {
    float* pp = par + (size_t)unit * 8;
    pp[0] = softplusf_(p[64]);
    pp[1] = sigmoidf_(p[65]);
    const float s0 = p[66], s1 = p[67], s2 = p[68];
    const float mx = fmaxf(s0, fmaxf(s1, s2));
    const float e0 = expf(s0 - mx), e1 = expf(s1 - mx), e2 = expf(s2 - mx);
    const float inv = 1.f / (e0 + e1 + e2);
    pp[2] = e0 * inv; pp[3] = e1 * inv; pp[4] = e2 * inv;
    pp[5] = 1.f + softplusf_(p[69]);
  }
  if (type == 1) {
    ea[((size_t)head * 512 + b) * 128 + lane] = sigmoidf_(p[70 + lane]);
    ea[((size_t)head * 512 + b) * 128 + 64 + lane] = tanhf(p[134 + lane]);
  }
}

// ---------------- streaming pass over a 64-row chunk of memory
// grid (CH_, B_); applies updates j<PASS in registers, emits cosine scores for
// head PASS (if <4), accumulates partial reads for head PASS-1 into readsP.
template <int PASS>
__global__ __launch_bounds__(256) void k_score(const float* __restrict__ mem0,
                                               const float* __restrict__ kn,
                                               const float* __restrict__ ea,
                                               const float* __restrict__ wbuf,
                                               float* __restrict__ sbuf,
                                               float* __restrict__ readsP) {
  const int chunk = blockIdx.x;
  const int b = blockIdx.y;
  const int tid = threadIdx.x;
  const int grp = tid >> 4, m4 = tid & 15;
  const int ms = m4 * 4;
  constexpr int NJ = (PASS > 0) ? PASS : 1;
  __shared__ float knr_s[64], knw_s[64];
  __shared__ float e_s[NJ][64], a_s[NJ][64];
  __shared__ float red[256][4];
  if (PASS < 4 && tid < 64) {
    knr_s[tid] = kn[((size_t)(0 * 4 + PASS) * 512 + b) * 64 + tid];
    knw_s[tid] = kn[((size_t)(1 * 4 + PASS) * 512 + b) * 64 + tid];
  }
  if (tid < 64) {
#pragma unroll
    for (int j = 0; j < PASS; ++j) {
      e_s[j][tid] = ea[((size_t)j * 512 + b) * 128 + tid];
      a_s[j][tid] = ea[((size_t)j * 512 + b) * 128 + 64 + tid];
    }
  }
  __syncthreads();
  float r0 = 0.f, r1 = 0.f, r2 = 0.f, r3 = 0.f;
#pragma unroll
  for (int it = 0; it < 64 / CH_; ++it) {
    const int n = chunk * (1024 / CH_) + it * 16 + grp;
    const float4 v0 = *(const float4*)&mem0[((size_t)b * 1024 + n) * 64 + ms];
    float vx = v0.x, vy = v0.y, vz = v0.z, vw = v0.w;
#pragma unroll
    for (int j = 0; j < PASS; ++j) {
      if (j == PASS - 1) {
        const float wr = wbuf[((size_t)j * 512 + b) * 1024 + n];
        r0 = fmaf(wr, vx, r0); r1 = fmaf(wr, vy, r1);
        r2 = fmaf(wr, vz, r2); r3 = fmaf(wr, vw, r3);
      }
      if (PASS < 4 || j < PASS - 1) {
        const float ww = wbuf[((size_t)(4 + j) * 512 + b) * 1024 + n];
        vx = vx * (1.f - ww * e_s[j][ms + 0]) + ww * a_s[j][ms + 0];
        vy = vy * (1.f - ww * e_s[j][ms + 1]) + ww * a_s[j][ms + 1];
        vz = vz * (1.f - ww * e_s[j][ms + 2]) + ww * a_s[j][ms + 2];
        vw = vw * (1.f - ww * e_s[j][ms + 3]) + ww * a_s[j][ms + 3];
      }
    }
    if (PASS < 4) {
      float ssq = vx * vx + vy * vy + vz * vz + vw * vw;
      float dr = vx * knr_s[ms] + vy * knr_s[ms + 1] + vz * knr_s[ms + 2] + vw * knr_s[ms + 3];
      float dw = vx * knw_s[ms] + vy * knw_s[ms + 1] + vz * knw_s[ms + 2] + vw * knw_s[ms + 3];
#pragma unroll
      for (int off = 1; off < 16; off <<= 1) {
        ssq += __shfl_xor(ssq, off);
        dr += __shfl_xor(dr, off);
        dw += __shfl_xor(dw, off);
      }
      if (m4 == 0) {
        const float inv = 1.f / (sqrtf(ssq) + EPS_);
        sbuf[((size_t)0 * 512 + b) * 1024 + n] = dr * inv;
        sbuf[((size_t)1 * 512 + b) * 1024 + n] = dw * inv;
      }
    }
  }
  if (PASS >= 1) {
    red[tid][0] = r0; red[tid][1] = r1; red[tid][2] = r2; red[tid][3] = r3;
    __syncthreads();
    if (tid < 16) {
      float s0 = 0.f, s1 = 0.f, s2 = 0.f, s3 = 0.f;
#pragma unroll
      for (int g2 = 0; g2 < 16; ++g2) {
        s0 += red[g2 * 16 + tid][0]; s1 += red[g2 * 16 + tid][1];
        s2 += red[g2 * 16 + tid][2]; s3 += red[g2 * 16 + tid][3];
      }
      float* rp = &readsP[(((size_t)(PASS - 1) * 512 + b) * CH_ + chunk) * 64 + tid * 4];
      rp[0] = s0; rp[1] = s1; rp[2] = s2; rp[3] = s3;
    }
  }
}

// ---------------- softmax + gate + shift + sharpen -> final weights
__global__ void k_finalize(const float* __restrict__ sbuf, const float* __restrict__ par,
                           const float* __restrict__ prev_w_r, const float* __restrict__ prev_w_w,
                           float* __restrict__ wbuf, int head) {
  const int b = blockIdx.x;
  const int type = blockIdx.y;
  const int tid = threadIdx.x;  // 256
  __shared__ float wg_s[1024];
  __shared__ float red_s[4];
  const float* pp = &par[((size_t)(type * 4 + head) * 512 + b) * 8];
  const float beta = pp[0], g = pp[1], sh0 = pp[2], sh1 = pp[3], sh2 = pp[4], gamma = pp[5];
  const float* srow = &sbuf[((size_t)type * 512 + b) * 1024];
  const float* prevw = ((type == 0) ? prev_w_r : prev_w_w) + ((size_t)head * 512 + b) * 1024;

  float z[4];
  float lmax = -1e30f;
#pragma unroll
  for (int k2 = 0; k2 < 4; ++k2) { z[k2] = beta * srow[tid + k2 * 256]; lmax = fmaxf(lmax, z[k2]); }
#pragma unroll
  for (int off = 32; off > 0; off >>= 1) lmax = fmaxf(lmax, __shfl_xor(lmax, off));
  if ((tid & 63) == 0) red_s[tid >> 6] = lmax;
  __syncthreads();
  const float gmax = fmaxf(fmaxf(red_s[0], red_s[1]), fmaxf(red_s[2], red_s[3]));
  __syncthreads();
  float ez[4]; float lsum = 0.f;
#pragma unroll
  for (int k2 = 0; k2 < 4; ++k2) { ez[k2] = expf(z[k2] - gmax); lsum += ez[k2]; }
#pragma unroll
  for (int off = 32; off > 0; off >>= 1) lsum += __shfl_xor(lsum, off);
  if ((tid & 63) == 0) red_s[tid >> 6] = lsum;
  __syncthreads();
  const float gsum = red_s[0] + red_s[1] + red_s[2] + red_s[3];
  const float invs = 1.f / gsum;
#pragma unroll
  for (int k2 = 0; k2 < 4; ++k2) {
    const int n = tid + k2 * 256;
    const float wc = ez[k2] * invs;
    wg_s[n] = g * wc + (1.f - g) * prevw[n];
  }
  __syncthreads();
  float wp[4]; float lsum2 = 0.f;
#pragma unroll
  for (int k2 = 0; k2 < 4; ++k2) {
    const int n = tid + k2 * 256;
    const float wsv = sh0 * wg_s[(n + 1023) & 1023] + sh1 * wg_s[n] + sh2 * wg_s[(n + 1) & 1023];
    wp[k2] = powf(wsv, gamma);
    lsum2 += wp[k2];
  }
#pragma unroll
  for (int off = 32; off > 0; off >>= 1) lsum2 += __shfl_xor(lsum2, off);
  if ((tid & 63) == 0) red_s[tid >> 6] = lsum2;
  __syncthreads();
  const float gsum2 = red_s[0] + red_s[1] + red_s[2] + red_s[3];
  const float inv2 = 1.f / (gsum2 + EPS_);
  float* wrow = &wbuf[((size_t)(type * 4 + head) * 512 + b) * 1024];
#pragma unroll
  for (int k2 = 0; k2 < 4; ++k2) wrow[tid + k2 * 256] = wp[k2] * inv2;
}

// ---------------- concat(h, reads) with final reads reduction over chunks
__global__ void k_aout(const float* __restrict__ h, const float* __restrict__ readsP,
                       float* __restrict__ Aout) {
  const int b = blockIdx.x;
  for (int j = threadIdx.x; j < 768; j += blockDim.x) {
    float v;
    if (j < 512) v = h[(size_t)b * 512 + j];
    else {
      const int jj = j - 512;
      const int head = jj >> 6, m = jj & 63;
      float s = 0.f;
#pragma unroll
      for (int c = 0; c < CH_; ++c)
        s += readsP[(((size_t)head * 512 + b) * CH_ + c) * 64 + m];
      v = s;
    }
    Aout[(size_t)b * 768 + j] = v;
  }
}

extern "C" void kernel_launch(void* const* d_in, const int* in_sizes, int n_in,
                              void* d_out, int out_size, void* d_ws, size_t ws_size,
                              hipStream_t stream) {
  (void)in_sizes; (void)n_in; (void)out_size; (void)ws_size;
  const float* in_data = (const float*)d_in[0];
  const float* memory = (const float*)d_in[1];
  const float* prev_reads = (const float*)d_in[2];
  const float* prev_w_r = (const float*)d_in[3];
  const float* prev_w_w = (const float*)d_in[4];
  const float* h0 = (const float*)d_in[5];
  const float* c0 = (const float*)d_in[6];
  const float* W_ih = (const float*)d_in[7];
  const float* b_ih = (const float*)d_in[8];
  const float* W_hh = (const float*)d_in[9];
  const float* b_hh = (const float*)d_in[10];
  const float* W_rh = (const float*)d_in[11];
  const float* b_rh = (const float*)d_in[12];
  const float* W_wh = (const float*)d_in[13];
  const float* b_wh = (const float*)d_in[14];
  const float* W_out = (const float*)d_in[15];
  const float* b_out = (const float*)d_in[16];
  float* out = (float*)d_out;

  float* ws = (float*)d_ws;
  float* x2 = ws;     ws += (size_t)512 * 1024;
  float* Wcat = ws;   ws += (size_t)2048 * 1024;
  float* bcat = ws;   ws += 2048;
  float* gates = ws;  ws += (size_t)512 * 2048;
  float* h = ws;      ws += (size_t)512 * 512;
  float* P = ws;      ws += (size_t)512 * 1072;
  float* kn = ws;     ws += (size_t)2 * 4 * 512 * 64;
  float* par = ws;    ws += (size_t)2 * 4 * 512 * 8;
  float* ea = ws;     ws += (size_t)4 * 512 * 128;
  float* sbuf = ws;   ws += (size_t)2 * 512 * 1024;
  float* wbuf = ws;   ws += (size_t)2 * 4 * 512 * 1024;
  float* readsP = ws; ws += (size_t)4 * 512 * CH_ * 64;
  float* Aout = ws;   ws += (size_t)512 * 768;

  k_prep_x2<<<512, 256, 0, stream>>>(in_data, prev_reads, h0, x2);
  k_prep_w<<<2048, 256, 0, stream>>>(W_ih, W_hh, b_ih, b_hh, Wcat, bcat);
  k_gemm<false><<<dim3(2048 / 64, 512 / 64), 256, 0, stream>>>(x2, Wcat, bcat, gates, 2048, 1024, 2048);
  k_lstm<<<512 * 512 / 256, 256, 0, stream>>>(gates, c0, h);
  k_gemm<false><<<dim3((280 + 63) / 64, 8), 256, 0, stream>>>(h, W_rh, b_rh, P, 280, 512, 1072);
  k_gemm<false><<<dim3((792 + 63) / 64, 8), 256, 0, stream>>>(h, W_wh, b_wh, P + 280, 792, 512, 1072);
  k_params<<<4096, 64, 0, stream>>>(P, kn, par, ea);

  const dim3 sgrid(CH_, 512);
  k_score<0><<<sgrid, 256, 0, stream>>>(memory, kn, ea, wbuf, sbuf, readsP);
  k_finalize<<<dim3(512, 2), 256, 0, stream>>>(sbuf, par, prev_w_r, prev_w_w, wbuf, 0);
  k_score<1><<<sgrid, 256, 0, stream>>>(memory, kn, ea, wbuf, sbuf, readsP);
  k_finalize<<<dim3(512, 2), 256, 0, stream>>>(sbuf, par, prev_w_r, prev_w_w, wbuf, 1);
  k_score<2><<<sgrid, 256, 0, stream>>>(memory, kn, ea, wbuf, sbuf, readsP);
  k_finalize<<<dim3(512, 2), 256, 0, stream>>>(sbuf, par, prev_w_r, prev_w_w, wbuf, 2);
  k_score<3><<<sgrid, 256, 0, stream>>>(memory, kn, ea, wbuf, sbuf, readsP);
  k_finalize<<<dim3(512, 2), 256, 0, stream>>>(sbuf, par, prev_w_r, prev_w_w, wbuf, 3);
  k_score<4><<<sgrid, 256, 0, stream>>>(memory, kn, ea, wbuf, sbuf, readsP);

  k_aout<<<512, 256, 0, stream>>>(h, readsP, Aout);
  k_gemm<true><<<dim3(256 / 64, 8), 256, 0, stream>>>(Aout, W_out, b_out, out, 256, 768, 256);
}

// Round 3
// 213.615 us; speedup vs baseline: 2.6900x; 1.6458x over previous
//
#include <hip/hip_runtime.h>
#include <cmath>

#define B_ 512
#define N_ 1024
#define M_ 64
#define H_ 512
#define NH_ 4
#define EPS_ 1e-8f
#define CH_ 16  // n-chunks per batch row in k_score

typedef __bf16 bf16x8 __attribute__((ext_vector_type(8)));
typedef float f32x4 __attribute__((ext_vector_type(4)));

__device__ __forceinline__ float sigmoidf_(float x) { return 1.f / (1.f + expf(-x)); }
__device__ __forceinline__ float softplusf_(float x) { return x > 20.f ? x : log1pf(expf(x)); }
__device__ __forceinline__ unsigned short f2bf(float x) {
  union { float f; unsigned u; } v; v.f = x;
  unsigned r = v.u + 0x7FFF + ((v.u >> 16) & 1);
  return (unsigned short)(r >> 16);
}

// ---------------- prep: x2b = bf16[ in_data | prev_reads(b-major) | h0 ]
__global__ void k_prep_x2(const float* __restrict__ in_data,
                          const float* __restrict__ prev_reads,
                          const float* __restrict__ h0,
                          unsigned short* __restrict__ x2b) {
  const int b = blockIdx.x;
  for (int j = threadIdx.x; j < 1024; j += blockDim.x) {
    float v;
    if (j < 256) v = in_data[(size_t)b * 256 + j];
    else if (j < 512) { int jj = j - 256; v = prev_reads[(size_t)(jj >> 6) * B_ * 64 + (size_t)b * 64 + (jj & 63)]; }
    else v = h0[(size_t)b * H_ + (j - 512)];
    x2b[(size_t)b * 1024 + j] = f2bf(v);
  }
}

// ---------------- Wcatb = bf16[W_ih | W_hh], bcat = b_ih + b_hh
__global__ void k_prep_w(const float* __restrict__ W_ih, const float* __restrict__ W_hh,
                         const float* __restrict__ b_ih, const float* __restrict__ b_hh,
                         unsigned short* __restrict__ Wcatb, float* __restrict__ bcat) {
  const int j = blockIdx.x;  // 0..2047
  for (int k = threadIdx.x; k < 1024; k += blockDim.x)
    Wcatb[(size_t)j * 1024 + k] = f2bf((k < 512) ? W_ih[(size_t)j * 512 + k] : W_hh[(size_t)j * 512 + (k - 512)]);
  if (threadIdx.x == 0) bcat[j] = b_ih[j] + b_hh[j];
}

// ---------------- convert W_rh|W_wh -> W2b[1072][512], W_out -> Woutb, bcat2 = [b_rh|b_wh]
__global__ void k_cvt_all(const float* __restrict__ W_rh, const float* __restrict__ W_wh,
                          const float* __restrict__ W_out,
                          const float* __restrict__ b_rh, const float* __restrict__ b_wh,
                          unsigned short* __restrict__ W2b, unsigned short* __restrict__ Woutb,
                          float* __restrict__ bcat2) {
  const int stride = gridDim.x * blockDim.x;
  const int t0 = blockIdx.x * blockDim.x + threadIdx.x;
  for (int i = t0; i < 143360; i += stride) W2b[i] = f2bf(W_rh[i]);
  for (int i = t0; i < 405504; i += stride) W2b[143360 + i] = f2bf(W_wh[i]);
  for (int i = t0; i < 196608; i += stride) Woutb[i] = f2bf(W_out[i]);
  for (int i = t0; i < 280; i += stride) bcat2[i] = b_rh[i];
  for (int i = t0; i < 792; i += stride) bcat2[280 + i] = b_wh[i];
}

// ---------------- bf16 MFMA GEMM, one wave per 32x32 tile, direct-from-global frags
// C[M,N] = A[M,K](bf16) * W[N,K](bf16)^T + bias ; optional sigmoid.
// grid = (ceil(N/32), M/32), block = 64.
template <bool SIG>
__global__ __launch_bounds__(64) void k_gemm_mfma(const unsigned short* __restrict__ A,
                                                  const unsigned short* __restrict__ W,
                                                  const float* __restrict__ bias,
                                                  float* __restrict__ C,
                                                  int Nn, int Kk, int ldc) {
  const int l = threadIdx.x;
  const int m0 = blockIdx.y * 32, n0 = blockIdx.x * 32;
  const int lr = l & 15, lk = (l >> 4) * 8;
  f32x4 acc00 = {0.f, 0.f, 0.f, 0.f}, acc01 = acc00, acc10 = acc00, acc11 = acc00;
  const size_t pa0 = (size_t)(m0 + lr) * Kk + lk;
  const size_t pa1 = pa0 + (size_t)16 * Kk;
  const bool bok0 = (n0 + lr) < Nn, bok1 = (n0 + 16 + lr) < Nn;
  const size_t pb0 = (size_t)(n0 + lr) * Kk + lk;
  const size_t pb1 = pb0 + (size_t)16 * Kk;
#pragma unroll 4
  for (int k0 = 0; k0 < Kk; k0 += 32) {
    bf16x8 a0 = *(const bf16x8*)(A + pa0 + k0);
    bf16x8 a1 = *(const bf16x8*)(A + pa1 + k0);
    bf16x8 b0 = {}, b1 = {};
    if (bok0) b0 = *(const bf16x8*)(W + pb0 + k0);
    if (bok1) b1 = *(const bf16x8*)(W + pb1 + k0);
    acc00 = __builtin_amdgcn_mfma_f32_16x16x32_bf16(a0, b0, acc00, 0, 0, 0);
    acc01 = __builtin_amdgcn_mfma_f32_16x16x32_bf16(a0, b1, acc01, 0, 0, 0);
    acc10 = __builtin_amdgcn_mfma_f32_16x16x32_bf16(a1, b0, acc10, 0, 0, 0);
    acc11 = __builtin_amdgcn_mfma_f32_16x16x32_bf16(a1, b1, acc11, 0, 0, 0);
  }
  const int orow = (l >> 4) * 4;
  f32x4 accs[2][2] = {{acc00, acc01}, {acc10, acc11}};
#pragma unroll
  for (int mi = 0; mi < 2; ++mi) {
#pragma unroll
    for (int nj = 0; nj < 2; ++nj) {
      const int n = n0 + nj * 16 + lr;
      if (n < Nn) {
        const float bv = bias[n];
#pragma unroll
        for (int r = 0; r < 4; ++r) {
          const int m = m0 + mi * 16 + orow + r;
          float v = accs[mi][nj][r] + bv;
          if (SIG) v = 1.f / (1.f + expf(-v));
          C[(size_t)m * ldc + n] = v;
        }
      }
    }
  }
}

// ---------------- LSTM pointwise -> h in bf16
__global__ void k_lstm(const float* __restrict__ gates, const float* __restrict__ c0,
                       unsigned short* __restrict__ hb) {
  const int idx = blockIdx.x * blockDim.x + threadIdx.x;  // < 512*512
  const int b = idx >> 9, j = idx & 511;
  const float* g = gates + (size_t)b * 2048;
  const float ig = g[j], fg = g[512 + j], gg = g[1024 + j], og = g[1536 + j];
  const float c = sigmoidf_(fg) * c0[idx] + sigmoidf_(ig) * tanhf(gg);
  hb[idx] = f2bf(sigmoidf_(og) * tanhf(c));
}

// ---------------- per-head params
__global__ void k_params(const float* __restrict__ P, float* __restrict__ kn,
                         float* __restrict__ par, float* __restrict__ ea) {
  const int unit = blockIdx.x;
  const int type = unit >> 11;
  const int rem = unit & 2047;
  const int head = rem >> 9;
  const int b = rem & 511;
  const int lane = threadIdx.x;  // 64
  const float* p = P + (size_t)b * 1072 + (type == 0 ? head * 70 : 280 + head * 198);
  const float kv = tanhf(p[lane]);
  float ss = kv * kv;
#pragma unroll
  for (int off = 32; off > 0; off >>= 1) ss += __shfl_xor(ss, off);
  kn[(size_t)unit * 64 + lane] = kv / (sqrtf(ss) + EPS_);
  if (lane == 0) {
    float* pp = par + (size_t)unit * 8;
    pp[0] = softplusf_(p[64]);
    pp[1] = sigmoidf_(p[65]);
    const float s0 = p[66], s1 = p[67], s2 = p[68];
    const float mx = fmaxf(s0, fmaxf(s1, s2));
    const float e0 = expf(s0 - mx), e1 = expf(s1 - mx), e2 = expf(s2 - mx);
    const float inv = 1.f / (e0 + e1 + e2);
    pp[2] = e0 * inv; pp[3] = e1 * inv; pp[4] = e2 * inv;
    pp[5] = 1.f + softplusf_(p[69]);
  }
  if (type == 1) {
    ea[((size_t)head * 512 + b) * 128 + lane] = sigmoidf_(p[70 + lane]);
    ea[((size_t)head * 512 + b) * 128 + 64 + lane] = tanhf(p[134 + lane]);
  }
}

// ---------------- streaming pass over a 64-row chunk of memory
template <int PASS>
__global__ __launch_bounds__(256) void k_score(const float* __restrict__ mem0,
                                               const float* __restrict__ kn,
                                               const float* __restrict__ ea,
                                               const float* __restrict__ wbuf,
                                               float* __restrict__ sbuf,
                                               float* __restrict__ readsP) {
  const int chunk = blockIdx.x;
  const int b = blockIdx.y;
  const int tid = threadIdx.x;
  const int grp = tid >> 4, m4 = tid & 15;
  const int ms = m4 * 4;
  const int wv = tid >> 6;
  const int nbase = chunk * 64;
  constexpr int NJ = (PASS > 0) ? PASS : 1;
  __shared__ float knr_s[64], knw_s[64];
  __shared__ float e_s[NJ][64], a_s[NJ][64];
  __shared__ float ww_s[NJ][64];
  __shared__ float wr_s[64];
  __shared__ float rws[4][64];
  if (PASS < 4 && tid < 64) {
    knr_s[tid] = kn[((size_t)(0 * 4 + PASS) * 512 + b) * 64 + tid];
    knw_s[tid] = kn[((size_t)(1 * 4 + PASS) * 512 + b) * 64 + tid];
  }
  if (tid < 64) {
#pragma unroll
    for (int j = 0; j < PASS; ++j) {
      e_s[j][tid] = ea[((size_t)j * 512 + b) * 128 + tid];
      a_s[j][tid] = ea[((size_t)j * 512 + b) * 128 + 64 + tid];
      ww_s[j][tid] = wbuf[((size_t)(4 + j) * 512 + b) * 1024 + nbase + tid];
    }
    if (PASS >= 1) wr_s[tid] = wbuf[((size_t)(PASS - 1) * 512 + b) * 1024 + nbase + tid];
  }
  __syncthreads();
  float r0 = 0.f, r1 = 0.f, r2 = 0.f, r3 = 0.f;
#pragma unroll
  for (int it = 0; it < 64 / CH_; ++it) {
    const int nl = it * 16 + grp;
    const int n = nbase + nl;
    const float4 v0 = *(const float4*)&mem0[((size_t)b * 1024 + n) * 64 + ms];
    float vx = v0.x, vy = v0.y, vz = v0.z, vw = v0.w;
#pragma unroll
    for (int j = 0; j < PASS; ++j) {
      if (j == PASS - 1) {
        const float wr = wr_s[nl];
        r0 = fmaf(wr, vx, r0); r1 = fmaf(wr, vy, r1);
        r2 = fmaf(wr, vz, r2); r3 = fmaf(wr, vw, r3);
      }
      if (PASS < 4 || j < PASS - 1) {
        const float ww = ww_s[j][nl];
        vx = vx * (1.f - ww * e_s[j][ms + 0]) + ww * a_s[j][ms + 0];
        vy = vy * (1.f - ww * e_s[j][ms + 1]) + ww * a_s[j][ms + 1];
        vz = vz * (1.f - ww * e_s[j][ms + 2]) + ww * a_s[j][ms + 2];
        vw = vw * (1.f - ww * e_s[j][ms + 3]) + ww * a_s[j][ms + 3];
      }
    }
    if (PASS < 4) {
      float ssq = vx * vx + vy * vy + vz * vz + vw * vw;
      float dr = vx * knr_s[ms] + vy * knr_s[ms + 1] + vz * knr_s[ms + 2] + vw * knr_s[ms + 3];
      float dw = vx * knw_s[ms] + vy * knw_s[ms + 1] + vz * knw_s[ms + 2] + vw * knw_s[ms + 3];
#pragma unroll
      for (int off = 1; off < 16; off <<= 1) {
        ssq += __shfl_xor(ssq, off);
        dr += __shfl_xor(dr, off);
        dw += __shfl_xor(dw, off);
      }
      if (m4 == 0) {
        const float inv = 1.f / (sqrtf(ssq) + EPS_);
        sbuf[((size_t)0 * 512 + b) * 1024 + n] = dr * inv;
        sbuf[((size_t)1 * 512 + b) * 1024 + n] = dw * inv;
      }
    }
  }
  if (PASS >= 1) {
    r0 += __shfl_xor(r0, 16); r1 += __shfl_xor(r1, 16);
    r2 += __shfl_xor(r2, 16); r3 += __shfl_xor(r3, 16);
    r0 += __shfl_xor(r0, 32); r1 += __shfl_xor(r1, 32);
    r2 += __shfl_xor(r2, 32); r3 += __shfl_xor(r3, 32);
    if ((tid & 63) < 16) {
      rws[wv][m4 * 4 + 0] = r0; rws[wv][m4 * 4 + 1] = r1;
      rws[wv][m4 * 4 + 2] = r2; rws[wv][m4 * 4 + 3] = r3;
    }
    __syncthreads();
    if (tid < 64) {
      const float s = rws[0][tid] + rws[1][tid] + rws[2][tid] + rws[3][tid];
      readsP[(((size_t)(PASS - 1) * 512 + b) * CH_ + chunk) * 64 + tid] = s;
    }
  }
}

// ---------------- softmax + gate + shift + sharpen -> final weights
__global__ void k_finalize(const float* __restrict__ sbuf, const float* __restrict__ par,
                           const float* __restrict__ prev_w_r, const float* __restrict__ prev_w_w,
                           float* __restrict__ wbuf, int head) {
  const int b = blockIdx.x;
  const int type = blockIdx.y;
  const int tid = threadIdx.x;  // 256
  __shared__ float wg_s[1024];
  __shared__ float red_s[4];
  const float* pp = &par[((size_t)(type * 4 + head) * 512 + b) * 8];
  const float beta = pp[0], g = pp[1], sh0 = pp[2], sh1 = pp[3], sh2 = pp[4], gamma = pp[5];
  const float* srow = &sbuf[((size_t)type * 512 + b) * 1024];
  const float* prevw = ((type == 0) ? prev_w_r : prev_w_w) + ((size_t)head * 512 + b) * 1024;

  float z[4];
  float lmax = -1e30f;
#pragma unroll
  for (int k2 = 0; k2 < 4; ++k2) { z[k2] = beta * srow[tid + k2 * 256]; lmax = fmaxf(lmax, z[k2]); }
#pragma unroll
  for (int off = 32; off > 0; off >>= 1) lmax = fmaxf(lmax, __shfl_xor(lmax, off));
  if ((tid & 63) == 0) red_s[tid >> 6] = lmax;
  __syncthreads();
  const float gmax = fmaxf(fmaxf(red_s[0], red_s[1]), fmaxf(red_s[2], red_s[3]));
  __syncthreads();
  float ez[4]; float lsum = 0.f;
#pragma unroll
  for (int k2 = 0; k2 < 4; ++k2) { ez[k2] = expf(z[k2] - gmax); lsum += ez[k2]; }
#pragma unroll
  for (int off = 32; off > 0; off >>= 1) lsum += __shfl_xor(lsum, off);
  if ((tid & 63) == 0) red_s[tid >> 6] = lsum;
  __syncthreads();
  const float gsum = red_s[0] + red_s[1] + red_s[2] + red_s[3];
  const float invs = 1.f / gsum;
#pragma unroll
  for (int k2 = 0; k2 < 4; ++k2) {
    const int n = tid + k2 * 256;
    const float wc = ez[k2] * invs;
    wg_s[n] = g * wc + (1.f - g) * prevw[n];
  }
  __syncthreads();
  float wp[4]; float lsum2 = 0.f;
#pragma unroll
  for (int k2 = 0; k2 < 4; ++k2) {
    const int n = tid + k2 * 256;
    const float wsv = sh0 * wg_s[(n + 1023) & 1023] + sh1 * wg_s[n] + sh2 * wg_s[(n + 1) & 1023];
    wp[k2] = (wsv > 0.f) ? exp2f(gamma * __log2f(wsv)) : 0.f;
    lsum2 += wp[k2];
  }
#pragma unroll
  for (int off = 32; off > 0; off >>= 1) lsum2 += __shfl_xor(lsum2, off);
  if ((tid & 63) == 0) red_s[tid >> 6] = lsum2;
  __syncthreads();
  const float gsum2 = red_s[0] + red_s[1] + red_s[2] + red_s[3];
  const float inv2 = 1.f / (gsum2 + EPS_);
  float* wrow = &wbuf[((size_t)(type * 4 + head) * 512 + b) * 1024];
#pragma unroll
  for (int k2 = 0; k2 < 4; ++k2) wrow[tid + k2 * 256] = wp[k2] * inv2;
}

// ---------------- Aout(bf16) = [h | reads], reads reduced over chunks
__global__ void k_aout(const unsigned short* __restrict__ hb, const float* __restrict__ readsP,
                       unsigned short* __restrict__ Aoutb) {
  const int b = blockIdx.x;
  for (int j = threadIdx.x; j < 768; j += blockDim.x) {
    unsigned short v;
    if (j < 512) v = hb[(size_t)b * 512 + j];
    else {
      const int jj = j - 512;
      const int head = jj >> 6, m = jj & 63;
      float s = 0.f;
#pragma unroll
      for (int c = 0; c < CH_; ++c)
        s += readsP[(((size_t)head * 512 + b) * CH_ + c) * 64 + m];
      v = f2bf(s);
    }
    Aoutb[(size_t)b * 768 + j] = v;
  }
}

extern "C" void kernel_launch(void* const* d_in, const int* in_sizes, int n_in,
                              void* d_out, int out_size, void* d_ws, size_t ws_size,
                              hipStream_t stream) {
  (void)in_sizes; (void)n_in; (void)out_size; (void)ws_size;
  const float* in_data = (const float*)d_in[0];
  const float* memory = (const float*)d_in[1];
  const float* prev_reads = (const float*)d_in[2];
  const float* prev_w_r = (const float*)d_in[3];
  const float* prev_w_w = (const float*)d_in[4];
  const float* h0 = (const float*)d_in[5];
  const float* c0 = (const float*)d_in[6];
  const float* W_ih = (const float*)d_in[7];
  const float* b_ih = (const float*)d_in[8];
  const float* W_hh = (const float*)d_in[9];
  const float* b_hh = (const float*)d_in[10];
  const float* W_rh = (const float*)d_in[11];
  const float* b_rh = (const float*)d_in[12];
  const float* W_wh = (const float*)d_in[13];
  const float* b_wh = (const float*)d_in[14];
  const float* W_out = (const float*)d_in[15];
  const float* b_out = (const float*)d_in[16];
  float* out = (float*)d_out;

  char* base = (char*)d_ws;
  auto alloc = [&](size_t bytes) -> char* {
    char* p = base; base += (bytes + 255) & ~(size_t)255; return p;
  };
  unsigned short* x2b   = (unsigned short*)alloc((size_t)512 * 1024 * 2);
  unsigned short* Wcatb = (unsigned short*)alloc((size_t)2048 * 1024 * 2);
  float* bcat           = (float*)alloc(2048 * 4);
  float* gates          = (float*)alloc((size_t)512 * 2048 * 4);
  unsigned short* hb    = (unsigned short*)alloc((size_t)512 * 512 * 2);
  unsigned short* W2b   = (unsigned short*)alloc((size_t)1072 * 512 * 2);
  float* bcat2          = (float*)alloc(1072 * 4);
  unsigned short* Woutb = (unsigned short*)alloc((size_t)256 * 768 * 2);
  float* P              = (float*)alloc((size_t)512 * 1072 * 4);
  float* kn             = (float*)alloc((size_t)8 * 512 * 64 * 4);
  float* par            = (float*)alloc((size_t)8 * 512 * 8 * 4);
  float* ea             = (float*)alloc((size_t)4 * 512 * 128 * 4);
  float* sbuf           = (float*)alloc((size_t)2 * 512 * 1024 * 4);
  float* wbuf           = (float*)alloc((size_t)8 * 512 * 1024 * 4);
  float* readsP         = (float*)alloc((size_t)4 * 512 * CH_ * 64 * 4);
  unsigned short* Aoutb = (unsigned short*)alloc((size_t)512 * 768 * 2);

  k_prep_x2<<<512, 256, 0, stream>>>(in_data, prev_reads, h0, x2b);
  k_prep_w<<<2048, 256, 0, stream>>>(W_ih, W_hh, b_ih, b_hh, Wcatb, bcat);
  k_cvt_all<<<512, 256, 0, stream>>>(W_rh, W_wh, W_out, b_rh, b_wh, W2b, Woutb, bcat2);

  k_gemm_mfma<false><<<dim3(2048 / 32, 512 / 32), 64, 0, stream>>>(x2b, Wcatb, bcat, gates, 2048, 1024, 2048);
  k_lstm<<<512 * 512 / 256, 256, 0, stream>>>(gates, c0, hb);
  k_gemm_mfma<false><<<dim3((1072 + 31) / 32, 512 / 32), 64, 0, stream>>>(hb, W2b, bcat2, P, 1072, 512, 1072);
  k_params<<<4096, 64, 0, stream>>>(P, kn, par, ea);

  const dim3 sgrid(CH_, 512);
  k_score<0><<<sgrid, 256, 0, stream>>>(memory, kn, ea, wbuf, sbuf, readsP);
  k_finalize<<<dim3(512, 2), 256, 0, stream>>>(sbuf, par, prev_w_r, prev_w_w, wbuf, 0);
  k_score<1><<<sgrid, 256, 0, stream>>>(memory, kn, ea, wbuf, sbuf, readsP);
  k_finalize<<<dim3(512, 2), 256, 0, stream>>>(sbuf, par, prev_w_r, prev_w_w, wbuf, 1);
  k_score<2><<<sgrid, 256, 0, stream>>>(memory, kn, ea, wbuf, sbuf, readsP);
  k_finalize<<<dim3(512, 2), 256, 0, stream>>>(sbuf, par, prev_w_r, prev_w_w, wbuf, 2);
  k_score<3><<<sgrid, 256, 0, stream>>>(memory, kn, ea, wbuf, sbuf, readsP);
  k_finalize<<<dim3(512, 2), 256, 0, stream>>>(sbuf, par, prev_w_r, prev_w_w, wbuf, 3);
  k_score<4><<<sgrid, 256, 0, stream>>>(memory, kn, ea, wbuf, sbuf, readsP);

  k_aout<<<512, 256, 0, stream>>>(hb, readsP, Aoutb);
  k_gemm_mfma<true><<<dim3(256 / 32, 512 / 32), 64, 0, stream>>>(Aoutb, Woutb, b_out, out, 256, 768, 256);
}

// Round 4
// 208.885 us; speedup vs baseline: 2.7509x; 1.0226x over previous
//
#include <hip/hip_runtime.h>
#include <cmath>

#define B_ 512
#define N_ 1024
#define M_ 64
#define H_ 512
#define NH_ 4
#define EPS_ 1e-8f
#define CH_ 16  // n-chunks per batch row in k_score

typedef __bf16 bf16x8 __attribute__((ext_vector_type(8)));
typedef float f32x4 __attribute__((ext_vector_type(4)));

__device__ __forceinline__ float sigmoidf_(float x) { return 1.f / (1.f + expf(-x)); }
__device__ __forceinline__ float softplusf_(float x) { return x > 20.f ? x : log1pf(expf(x)); }
__device__ __forceinline__ unsigned short f2bf(float x) {
  union { float f; unsigned u; } v; v.f = x;
  unsigned r = v.u + 0x7FFF + ((v.u >> 16) & 1);
  return (unsigned short)(r >> 16);
}

// ---------------- prep: x2b = bf16[ in_data | prev_reads(b-major) | h0 ]
__global__ void k_prep_x2(const float* __restrict__ in_data,
                          const float* __restrict__ prev_reads,
                          const float* __restrict__ h0,
                          unsigned short* __restrict__ x2b) {
  const int b = blockIdx.x;
  for (int j = threadIdx.x; j < 1024; j += blockDim.x) {
    float v;
    if (j < 256) v = in_data[(size_t)b * 256 + j];
    else if (j < 512) { int jj = j - 256; v = prev_reads[(size_t)(jj >> 6) * B_ * 64 + (size_t)b * 64 + (jj & 63)]; }
    else v = h0[(size_t)b * H_ + (j - 512)];
    x2b[(size_t)b * 1024 + j] = f2bf(v);
  }
}

// ---------------- all weight conversions fused (grid-stride)
__global__ void k_prep_weights(const float* __restrict__ W_ih, const float* __restrict__ W_hh,
                               const float* __restrict__ b_ih, const float* __restrict__ b_hh,
                               const float* __restrict__ W_rh, const float* __restrict__ W_wh,
                               const float* __restrict__ W_out,
                               const float* __restrict__ b_rh, const float* __restrict__ b_wh,
                               unsigned short* __restrict__ Wcatb, float* __restrict__ bcat,
                               unsigned short* __restrict__ W2b, unsigned short* __restrict__ Woutb,
                               float* __restrict__ bcat2) {
  const int stride = gridDim.x * blockDim.x;
  const int t0 = blockIdx.x * blockDim.x + threadIdx.x;
  for (int i = t0; i < 2048 * 1024; i += stride) {
    const int j = i >> 10, k = i & 1023;
    Wcatb[i] = f2bf(k < 512 ? W_ih[(size_t)j * 512 + k] : W_hh[(size_t)j * 512 + (k - 512)]);
  }
  for (int i = t0; i < 2048; i += stride) bcat[i] = b_ih[i] + b_hh[i];
  for (int i = t0; i < 143360; i += stride) W2b[i] = f2bf(W_rh[i]);
  for (int i = t0; i < 405504; i += stride) W2b[143360 + i] = f2bf(W_wh[i]);
  for (int i = t0; i < 196608; i += stride) Woutb[i] = f2bf(W_out[i]);
  for (int i = t0; i < 280; i += stride) bcat2[i] = b_rh[i];
  for (int i = t0; i < 792; i += stride) bcat2[280 + i] = b_wh[i];
}

// ---------------- bf16 MFMA GEMM, one wave per 32x32 tile, direct-from-global frags
template <bool SIG>
__global__ __launch_bounds__(64) void k_gemm_mfma(const unsigned short* __restrict__ A,
                                                  const unsigned short* __restrict__ W,
                                                  const float* __restrict__ bias,
                                                  float* __restrict__ C,
                                                  int Nn, int Kk, int ldc) {
  const int l = threadIdx.x;
  const int m0 = blockIdx.y * 32, n0 = blockIdx.x * 32;
  const int lr = l & 15, lk = (l >> 4) * 8;
  f32x4 acc00 = {0.f, 0.f, 0.f, 0.f}, acc01 = acc00, acc10 = acc00, acc11 = acc00;
  const size_t pa0 = (size_t)(m0 + lr) * Kk + lk;
  const size_t pa1 = pa0 + (size_t)16 * Kk;
  const bool bok0 = (n0 + lr) < Nn, bok1 = (n0 + 16 + lr) < Nn;
  const size_t pb0 = (size_t)(n0 + lr) * Kk + lk;
  const size_t pb1 = pb0 + (size_t)16 * Kk;
#pragma unroll 4
  for (int k0 = 0; k0 < Kk; k0 += 32) {
    bf16x8 a0 = *(const bf16x8*)(A + pa0 + k0);
    bf16x8 a1 = *(const bf16x8*)(A + pa1 + k0);
    bf16x8 b0 = {}, b1 = {};
    if (bok0) b0 = *(const bf16x8*)(W + pb0 + k0);
    if (bok1) b1 = *(const bf16x8*)(W + pb1 + k0);
    acc00 = __builtin_amdgcn_mfma_f32_16x16x32_bf16(a0, b0, acc00, 0, 0, 0);
    acc01 = __builtin_amdgcn_mfma_f32_16x16x32_bf16(a0, b1, acc01, 0, 0, 0);
    acc10 = __builtin_amdgcn_mfma_f32_16x16x32_bf16(a1, b0, acc10, 0, 0, 0);
    acc11 = __builtin_amdgcn_mfma_f32_16x16x32_bf16(a1, b1, acc11, 0, 0, 0);
  }
  const int orow = (l >> 4) * 4;
  f32x4 accs[2][2] = {{acc00, acc01}, {acc10, acc11}};
#pragma unroll
  for (int mi = 0; mi < 2; ++mi) {
#pragma unroll
    for (int nj = 0; nj < 2; ++nj) {
      const int n = n0 + nj * 16 + lr;
      if (n < Nn) {
        const float bv = bias[n];
#pragma unroll
        for (int r = 0; r < 4; ++r) {
          const int m = m0 + mi * 16 + orow + r;
          float v = accs[mi][nj][r] + bv;
          if (SIG) v = 1.f / (1.f + expf(-v));
          C[(size_t)m * ldc + n] = v;
        }
      }
    }
  }
}

// ---------------- LSTM pointwise -> h in bf16
__global__ void k_lstm(const float* __restrict__ gates, const float* __restrict__ c0,
                       unsigned short* __restrict__ hb) {
  const int idx = blockIdx.x * blockDim.x + threadIdx.x;  // < 512*512
  const int b = idx >> 9, j = idx & 511;
  const float* g = gates + (size_t)b * 2048;
  const float ig = g[j], fg = g[512 + j], gg = g[1024 + j], og = g[1536 + j];
  const float c = sigmoidf_(fg) * c0[idx] + sigmoidf_(ig) * tanhf(gg);
  hb[idx] = f2bf(sigmoidf_(og) * tanhf(c));
}

// ---------------- per-head params
__global__ void k_params(const float* __restrict__ P, float* __restrict__ kn,
                         float* __restrict__ par, float* __restrict__ ea) {
  const int unit = blockIdx.x;
  const int type = unit >> 11;
  const int rem = unit & 2047;
  const int head = rem >> 9;
  const int b = rem & 511;
  const int lane = threadIdx.x;  // 64
  const float* p = P + (size_t)b * 1072 + (type == 0 ? head * 70 : 280 + head * 198);
  const float kv = tanhf(p[lane]);
  float ss = kv * kv;
#pragma unroll
  for (int off = 32; off > 0; off >>= 1) ss += __shfl_xor(ss, off);
  kn[(size_t)unit * 64 + lane] = kv / (sqrtf(ss) + EPS_);
  if (lane == 0) {
    float* pp = par + (size_t)unit * 8;
    pp[0] = softplusf_(p[64]);
    pp[1] = sigmoidf_(p[65]);
    const float s0 = p[66], s1 = p[67], s2 = p[68];
    const float mx = fmaxf(s0, fmaxf(s1, s2));
    const float e0 = expf(s0 - mx), e1 = expf(s1 - mx), e2 = expf(s2 - mx);
    const float inv = 1.f / (e0 + e1 + e2);
    pp[2] = e0 * inv; pp[3] = e1 * inv; pp[4] = e2 * inv;
    pp[5] = 1.f + softplusf_(p[69]);
  }
  if (type == 1) {
    ea[((size_t)head * 512 + b) * 128 + lane] = sigmoidf_(p[70 + lane]);
    ea[((size_t)head * 512 + b) * 128 + 64 + lane] = tanhf(p[134 + lane]);
  }
}

// ---------------- streaming pass over a 64-row chunk of memory (8 cols/thread)
// PASS 0 reads f32 memory, scores at f32 precision, writes bf16 image.
// PASS>=1 reads bf16 image, applies updates j<PASS in registers.
template <int PASS>
__global__ __launch_bounds__(256) void k_score(const float* __restrict__ mem0,
                                               unsigned short* __restrict__ membf,
                                               const float* __restrict__ kn,
                                               const float* __restrict__ ea,
                                               const float* __restrict__ wbuf,
                                               float* __restrict__ sbuf,
                                               float* __restrict__ readsP) {
  const int chunk = blockIdx.x;
  const int b = blockIdx.y;
  const int tid = threadIdx.x;
  const int grp = tid >> 3, m8 = tid & 7;
  const int c0 = m8 * 8;
  const int wv = tid >> 6;
  const int nbase = chunk * 64;
  constexpr int NJ = (PASS > 0) ? PASS : 1;
  __shared__ float knr_s[64], knw_s[64];
  __shared__ float e_s[NJ][64], a_s[NJ][64];
  __shared__ float ww_s[NJ][64];
  __shared__ float wr_s[64];
  __shared__ float rws[4][64];
  if (PASS < 4 && tid < 64) {
    knr_s[tid] = kn[((size_t)(0 * 4 + PASS) * 512 + b) * 64 + tid];
    knw_s[tid] = kn[((size_t)(1 * 4 + PASS) * 512 + b) * 64 + tid];
  }
  if (tid < 64) {
#pragma unroll
    for (int j = 0; j < PASS; ++j) {
      e_s[j][tid] = ea[((size_t)j * 512 + b) * 128 + tid];
      a_s[j][tid] = ea[((size_t)j * 512 + b) * 128 + 64 + tid];
      ww_s[j][tid] = wbuf[((size_t)(4 + j) * 512 + b) * 1024 + nbase + tid];
    }
    if (PASS >= 1) wr_s[tid] = wbuf[((size_t)(PASS - 1) * 512 + b) * 1024 + nbase + tid];
  }
  __syncthreads();
  float r[8] = {0.f, 0.f, 0.f, 0.f, 0.f, 0.f, 0.f, 0.f};
#pragma unroll
  for (int it = 0; it < 2; ++it) {
    const int nl = it * 32 + grp;
    const int n = nbase + nl;
    float v[8];
    if (PASS == 0) {
      const float4 u0 = *(const float4*)&mem0[((size_t)b * 1024 + n) * 64 + c0];
      const float4 u1 = *(const float4*)&mem0[((size_t)b * 1024 + n) * 64 + c0 + 4];
      v[0] = u0.x; v[1] = u0.y; v[2] = u0.z; v[3] = u0.w;
      v[4] = u1.x; v[5] = u1.y; v[6] = u1.z; v[7] = u1.w;
      uint4 st;
      st.x = (unsigned)f2bf(v[0]) | ((unsigned)f2bf(v[1]) << 16);
      st.y = (unsigned)f2bf(v[2]) | ((unsigned)f2bf(v[3]) << 16);
      st.z = (unsigned)f2bf(v[4]) | ((unsigned)f2bf(v[5]) << 16);
      st.w = (unsigned)f2bf(v[6]) | ((unsigned)f2bf(v[7]) << 16);
      *(uint4*)&membf[((size_t)b * 1024 + n) * 64 + c0] = st;
    } else {
      const uint4 u = *(const uint4*)&membf[((size_t)b * 1024 + n) * 64 + c0];
      v[0] = __uint_as_float(u.x << 16); v[1] = __uint_as_float(u.x & 0xffff0000u);
      v[2] = __uint_as_float(u.y << 16); v[3] = __uint_as_float(u.y & 0xffff0000u);
      v[4] = __uint_as_float(u.z << 16); v[5] = __uint_as_float(u.z & 0xffff0000u);
      v[6] = __uint_as_float(u.w << 16); v[7] = __uint_as_float(u.w & 0xffff0000u);
    }
#pragma unroll
    for (int j = 0; j < PASS; ++j) {
      if (j == PASS - 1) {
        const float wr = wr_s[nl];
#pragma unroll
        for (int c = 0; c < 8; ++c) r[c] = fmaf(wr, v[c], r[c]);
      }
      if (PASS < 4 || j < PASS - 1) {
        const float ww = ww_s[j][nl];
#pragma unroll
        for (int c = 0; c < 8; ++c)
          v[c] = v[c] * (1.f - ww * e_s[j][c0 + c]) + ww * a_s[j][c0 + c];
      }
    }
    if (PASS < 4) {
      float ssq = 0.f, dr = 0.f, dw = 0.f;
#pragma unroll
      for (int c = 0; c < 8; ++c) {
        ssq = fmaf(v[c], v[c], ssq);
        dr = fmaf(v[c], knr_s[c0 + c], dr);
        dw = fmaf(v[c], knw_s[c0 + c], dw);
      }
#pragma unroll
      for (int off = 1; off < 8; off <<= 1) {
        ssq += __shfl_xor(ssq, off);
        dr += __shfl_xor(dr, off);
        dw += __shfl_xor(dw, off);
      }
      if (m8 == 0) {
        const float inv = 1.f / (sqrtf(ssq) + EPS_);
        sbuf[((size_t)0 * 512 + b) * 1024 + n] = dr * inv;
        sbuf[((size_t)1 * 512 + b) * 1024 + n] = dw * inv;
      }
    }
  }
  if (PASS >= 1) {
#pragma unroll
    for (int c = 0; c < 8; ++c) {
      r[c] += __shfl_xor(r[c], 8);
      r[c] += __shfl_xor(r[c], 16);
      r[c] += __shfl_xor(r[c], 32);
    }
    if ((tid & 63) < 8) {
#pragma unroll
      for (int c = 0; c < 8; ++c) rws[wv][c0 + c] = r[c];
    }
    __syncthreads();
    if (tid < 64) {
      const float s = rws[0][tid] + rws[1][tid] + rws[2][tid] + rws[3][tid];
      readsP[(((size_t)(PASS - 1) * 512 + b) * CH_ + chunk) * 64 + tid] = s;
    }
  }
}

// ---------------- softmax + gate + shift + sharpen -> final weights
__global__ void k_finalize(const float* __restrict__ sbuf, const float* __restrict__ par,
                           const float* __restrict__ prev_w_r, const float* __restrict__ prev_w_w,
                           float* __restrict__ wbuf, int head) {
  const int b = blockIdx.x;
  const int type = blockIdx.y;
  const int tid = threadIdx.x;  // 256
  __shared__ float wg_s[1024];
  __shared__ float red_s[4];
  const float* pp = &par[((size_t)(type * 4 + head) * 512 + b) * 8];
  const float beta = pp[0], g = pp[1], sh0 = pp[2], sh1 = pp[3], sh2 = pp[4], gamma = pp[5];
  const float* srow = &sbuf[((size_t)type * 512 + b) * 1024];
  const float* prevw = ((type == 0) ? prev_w_r : prev_w_w) + ((size_t)head * 512 + b) * 1024;

  float z[4];
  float lmax = -1e30f;
#pragma unroll
  for (int k2 = 0; k2 < 4; ++k2) { z[k2] = beta * srow[tid + k2 * 256]; lmax = fmaxf(lmax, z[k2]); }
#pragma unroll
  for (int off = 32; off > 0; off >>= 1) lmax = fmaxf(lmax, __shfl_xor(lmax, off));
  if ((tid & 63) == 0) red_s[tid >> 6] = lmax;
  __syncthreads();
  const float gmax = fmaxf(fmaxf(red_s[0], red_s[1]), fmaxf(red_s[2], red_s[3]));
  __syncthreads();
  float ez[4]; float lsum = 0.f;
#pragma unroll
  for (int k2 = 0; k2 < 4; ++k2) { ez[k2] = expf(z[k2] - gmax); lsum += ez[k2]; }
#pragma unroll
  for (int off = 32; off > 0; off >>= 1) lsum += __shfl_xor(lsum, off);
  if ((tid & 63) == 0) red_s[tid >> 6] = lsum;
  __syncthreads();
  const float gsum = red_s[0] + red_s[1] + red_s[2] + red_s[3];
  const float invs = 1.f / gsum;
#pragma unroll
  for (int k2 = 0; k2 < 4; ++k2) {
    const int n = tid + k2 * 256;
    const float wc = ez[k2] * invs;
    wg_s[n] = g * wc + (1.f - g) * prevw[n];
  }
  __syncthreads();
  float wp[4]; float lsum2 = 0.f;
#pragma unroll
  for (int k2 = 0; k2 < 4; ++k2) {
    const int n = tid + k2 * 256;
    const float wsv = sh0 * wg_s[(n + 1023) & 1023] + sh1 * wg_s[n] + sh2 * wg_s[(n + 1) & 1023];
    wp[k2] = (wsv > 0.f) ? exp2f(gamma * __log2f(wsv)) : 0.f;
    lsum2 += wp[k2];
  }
#pragma unroll
  for (int off = 32; off > 0; off >>= 1) lsum2 += __shfl_xor(lsum2, off);
  if ((tid & 63) == 0) red_s[tid >> 6] = lsum2;
  __syncthreads();
  const float gsum2 = red_s[0] + red_s[1] + red_s[2] + red_s[3];
  const float inv2 = 1.f / (gsum2 + EPS_);
  float* wrow = &wbuf[((size_t)(type * 4 + head) * 512 + b) * 1024];
#pragma unroll
  for (int k2 = 0; k2 < 4; ++k2) wrow[tid + k2 * 256] = wp[k2] * inv2;
}

// ---------------- Aout(bf16) = [h | reads], reads reduced over chunks
__global__ void k_aout(const unsigned short* __restrict__ hb, const float* __restrict__ readsP,
                       unsigned short* __restrict__ Aoutb) {
  const int b = blockIdx.x;
  for (int j = threadIdx.x; j < 768; j += blockDim.x) {
    unsigned short v;
    if (j < 512) v = hb[(size_t)b * 512 + j];
    else {
      const int jj = j - 512;
      const int head = jj >> 6, m = jj & 63;
      float s = 0.f;
#pragma unroll
      for (int c = 0; c < CH_; ++c)
        s += readsP[(((size_t)head * 512 + b) * CH_ + c) * 64 + m];
      v = f2bf(s);
    }
    Aoutb[(size_t)b * 768 + j] = v;
  }
}

extern "C" void kernel_launch(void* const* d_in, const int* in_sizes, int n_in,
                              void* d_out, int out_size, void* d_ws, size_t ws_size,
                              hipStream_t stream) {
  (void)in_sizes; (void)n_in; (void)out_size; (void)ws_size;
  const float* in_data = (const float*)d_in[0];
  const float* memory = (const float*)d_in[1];
  const float* prev_reads = (const float*)d_in[2];
  const float* prev_w_r = (const float*)d_in[3];
  const float* prev_w_w = (const float*)d_in[4];
  const float* h0 = (const float*)d_in[5];
  const float* c0 = (const float*)d_in[6];
  const float* W_ih = (const float*)d_in[7];
  const float* b_ih = (const float*)d_in[8];
  const float* W_hh = (const float*)d_in[9];
  const float* b_hh = (const float*)d_in[10];
  const float* W_rh = (const float*)d_in[11];
  const float* b_rh = (const float*)d_in[12];
  const float* W_wh = (const float*)d_in[13];
  const float* b_wh = (const float*)d_in[14];
  const float* W_out = (const float*)d_in[15];
  const float* b_out = (const float*)d_in[16];
  float* out = (float*)d_out;

  char* base = (char*)d_ws;
  auto alloc = [&](size_t bytes) -> char* {
    char* p = base; base += (bytes + 255) & ~(size_t)255; return p;
  };
  unsigned short* x2b   = (unsigned short*)alloc((size_t)512 * 1024 * 2);
  unsigned short* Wcatb = (unsigned short*)alloc((size_t)2048 * 1024 * 2);
  float* bcat           = (float*)alloc(2048 * 4);
  float* gates          = (float*)alloc((size_t)512 * 2048 * 4);
  unsigned short* hb    = (unsigned short*)alloc((size_t)512 * 512 * 2);
  unsigned short* W2b   = (unsigned short*)alloc((size_t)1072 * 512 * 2);
  float* bcat2          = (float*)alloc(1072 * 4);
  unsigned short* Woutb = (unsigned short*)alloc((size_t)256 * 768 * 2);
  float* P              = (float*)alloc((size_t)512 * 1072 * 4);
  float* kn             = (float*)alloc((size_t)8 * 512 * 64 * 4);
  float* par            = (float*)alloc((size_t)8 * 512 * 8 * 4);
  float* ea             = (float*)alloc((size_t)4 * 512 * 128 * 4);
  float* sbuf           = (float*)alloc((size_t)2 * 512 * 1024 * 4);
  float* wbuf           = (float*)alloc((size_t)8 * 512 * 1024 * 4);
  float* readsP         = (float*)alloc((size_t)4 * 512 * CH_ * 64 * 4);
  unsigned short* Aoutb = (unsigned short*)alloc((size_t)512 * 768 * 2);
  unsigned short* membf = (unsigned short*)alloc((size_t)512 * 1024 * 64 * 2);

  k_prep_x2<<<512, 256, 0, stream>>>(in_data, prev_reads, h0, x2b);
  k_prep_weights<<<1024, 256, 0, stream>>>(W_ih, W_hh, b_ih, b_hh, W_rh, W_wh, W_out,
                                           b_rh, b_wh, Wcatb, bcat, W2b, Woutb, bcat2);

  k_gemm_mfma<false><<<dim3(2048 / 32, 512 / 32), 64, 0, stream>>>(x2b, Wcatb, bcat, gates, 2048, 1024, 2048);
  k_lstm<<<512 * 512 / 256, 256, 0, stream>>>(gates, c0, hb);
  k_gemm_mfma<false><<<dim3((1072 + 31) / 32, 512 / 32), 64, 0, stream>>>(hb, W2b, bcat2, P, 1072, 512, 1072);
  k_params<<<4096, 64, 0, stream>>>(P, kn, par, ea);

  const dim3 sgrid(CH_, 512);
  k_score<0><<<sgrid, 256, 0, stream>>>(memory, membf, kn, ea, wbuf, sbuf, readsP);
  k_finalize<<<dim3(512, 2), 256, 0, stream>>>(sbuf, par, prev_w_r, prev_w_w, wbuf, 0);
  k_score<1><<<sgrid, 256, 0, stream>>>(memory, membf, kn, ea, wbuf, sbuf, readsP);
  k_finalize<<<dim3(512, 2), 256, 0, stream>>>(sbuf, par, prev_w_r, prev_w_w, wbuf, 1);
  k_score<2><<<sgrid, 256, 0, stream>>>(memory, membf, kn, ea, wbuf, sbuf, readsP);
  k_finalize<<<dim3(512, 2), 256, 0, stream>>>(sbuf, par, prev_w_r, prev_w_w, wbuf, 2);
  k_score<3><<<sgrid, 256, 0, stream>>>(memory, membf, kn, ea, wbuf, sbuf, readsP);
  k_finalize<<<dim3(512, 2), 256, 0, stream>>>(sbuf, par, prev_w_r, prev_w_w, wbuf, 3);
  k_score<4><<<sgrid, 256, 0, stream>>>(memory, membf, kn, ea, wbuf, sbuf, readsP);

  k_aout<<<512, 256, 0, stream>>>(hb, readsP, Aoutb);
  k_gemm_mfma<true><<<dim3(256 / 32, 512 / 32), 64, 0, stream>>>(Aoutb, Woutb, b_out, out, 256, 768, 256);
}

// Round 5
// 179.547 us; speedup vs baseline: 3.2003x; 1.1634x over previous
//
#include <hip/hip_runtime.h>
#include <cmath>

#define B_ 512
#define N_ 1024
#define EPS_ 1e-8f

typedef __bf16 bf16x8 __attribute__((ext_vector_type(8)));
typedef float f32x4 __attribute__((ext_vector_type(4)));

__device__ __forceinline__ float sigmoidf_(float x) { return 1.f / (1.f + expf(-x)); }
__device__ __forceinline__ float softplusf_(float x) { return x > 20.f ? x : log1pf(expf(x)); }
__device__ __forceinline__ unsigned f2bf(float x) {
  union { float f; unsigned u; } v; v.f = x;
  unsigned r = v.u + 0x7FFF + ((v.u >> 16) & 1);
  return r >> 16;
}
__device__ __forceinline__ float bfhi2f(unsigned u) { return __uint_as_float(u & 0xffff0000u); }
__device__ __forceinline__ float bflo2f(unsigned u) { return __uint_as_float(u << 16); }

// ---------------- one prep kernel: x2b + all weight conversions (grid-stride)
__global__ void k_prep(const float* __restrict__ in_data, const float* __restrict__ prev_reads,
                       const float* __restrict__ h0,
                       const float* __restrict__ W_ih, const float* __restrict__ W_hh,
                       const float* __restrict__ b_ih, const float* __restrict__ b_hh,
                       const float* __restrict__ W_rh, const float* __restrict__ W_wh,
                       const float* __restrict__ W_out,
                       const float* __restrict__ b_rh, const float* __restrict__ b_wh,
                       unsigned short* __restrict__ x2b,
                       unsigned short* __restrict__ Wcatb, float* __restrict__ bcat,
                       unsigned short* __restrict__ W2b, unsigned short* __restrict__ Woutb,
                       float* __restrict__ bcat2) {
  const int stride = gridDim.x * blockDim.x;
  const int t0 = blockIdx.x * blockDim.x + threadIdx.x;
  for (int i = t0; i < 512 * 1024; i += stride) {
    const int b = i >> 10, j = i & 1023;
    float v;
    if (j < 256) v = in_data[(size_t)b * 256 + j];
    else if (j < 512) { const int jj = j - 256; v = prev_reads[(size_t)(jj >> 6) * B_ * 64 + (size_t)b * 64 + (jj & 63)]; }
    else v = h0[(size_t)b * 512 + (j - 512)];
    x2b[i] = (unsigned short)f2bf(v);
  }
  for (int i = t0; i < 2048 * 1024; i += stride) {
    const int j = i >> 10, k = i & 1023;
    Wcatb[i] = (unsigned short)f2bf(k < 512 ? W_ih[(size_t)j * 512 + k] : W_hh[(size_t)j * 512 + (k - 512)]);
  }
  for (int i = t0; i < 2048; i += stride) bcat[i] = b_ih[i] + b_hh[i];
  for (int i = t0; i < 143360; i += stride) W2b[i] = (unsigned short)f2bf(W_rh[i]);
  for (int i = t0; i < 405504; i += stride) W2b[143360 + i] = (unsigned short)f2bf(W_wh[i]);
  for (int i = t0; i < 196608; i += stride) Woutb[i] = (unsigned short)f2bf(W_out[i]);
  for (int i = t0; i < 280; i += stride) bcat2[i] = b_rh[i];
  for (int i = t0; i < 792; i += stride) bcat2[280 + i] = b_wh[i];
}

// ---------------- bf16 MFMA GEMM, one wave per 32x32 tile, direct-from-global frags
// C[M,N] = A[M,K](bf16, row stride lda) * W[N,K](bf16)^T + bias ; optional sigmoid.
template <bool SIG>
__global__ __launch_bounds__(64) void k_gemm_mfma(const unsigned short* __restrict__ A, int lda,
                                                  const unsigned short* __restrict__ W,
                                                  const float* __restrict__ bias,
                                                  float* __restrict__ C,
                                                  int Nn, int Kk, int ldc) {
  const int l = threadIdx.x;
  const int m0 = blockIdx.y * 32, n0 = blockIdx.x * 32;
  const int lr = l & 15, lk = (l >> 4) * 8;
  f32x4 acc00 = {0.f, 0.f, 0.f, 0.f}, acc01 = acc00, acc10 = acc00, acc11 = acc00;
  const size_t pa0 = (size_t)(m0 + lr) * lda + lk;
  const size_t pa1 = pa0 + (size_t)16 * lda;
  const bool bok0 = (n0 + lr) < Nn, bok1 = (n0 + 16 + lr) < Nn;
  const size_t pb0 = (size_t)(n0 + lr) * Kk + lk;
  const size_t pb1 = pb0 + (size_t)16 * Kk;
#pragma unroll 4
  for (int k0 = 0; k0 < Kk; k0 += 32) {
    bf16x8 a0 = *(const bf16x8*)(A + pa0 + k0);
    bf16x8 a1 = *(const bf16x8*)(A + pa1 + k0);
    bf16x8 b0 = {}, b1 = {};
    if (bok0) b0 = *(const bf16x8*)(W + pb0 + k0);
    if (bok1) b1 = *(const bf16x8*)(W + pb1 + k0);
    acc00 = __builtin_amdgcn_mfma_f32_16x16x32_bf16(a0, b0, acc00, 0, 0, 0);
    acc01 = __builtin_amdgcn_mfma_f32_16x16x32_bf16(a0, b1, acc01, 0, 0, 0);
    acc10 = __builtin_amdgcn_mfma_f32_16x16x32_bf16(a1, b0, acc10, 0, 0, 0);
    acc11 = __builtin_amdgcn_mfma_f32_16x16x32_bf16(a1, b1, acc11, 0, 0, 0);
  }
  const int orow = (l >> 4) * 4;
  f32x4 accs[2][2] = {{acc00, acc01}, {acc10, acc11}};
#pragma unroll
  for (int mi = 0; mi < 2; ++mi) {
#pragma unroll
    for (int nj = 0; nj < 2; ++nj) {
      const int n = n0 + nj * 16 + lr;
      if (n < Nn) {
        const float bv = bias[n];
#pragma unroll
        for (int r = 0; r < 4; ++r) {
          const int m = m0 + mi * 16 + orow + r;
          float v = accs[mi][nj][r] + bv;
          if (SIG) v = 1.f / (1.f + expf(-v));
          C[(size_t)m * ldc + n] = v;
        }
      }
    }
  }
}

// ---------------- LSTM pointwise -> h (bf16) into Aoutb rows (stride 768)
__global__ void k_lstm(const float* __restrict__ gates, const float* __restrict__ c0,
                       unsigned short* __restrict__ Aoutb) {
  const int idx = blockIdx.x * blockDim.x + threadIdx.x;  // < 512*512
  const int b = idx >> 9, j = idx & 511;
  const float* g = gates + (size_t)b * 2048;
  const float ig = g[j], fg = g[512 + j], gg = g[1024 + j], og = g[1536 + j];
  const float c = sigmoidf_(fg) * c0[idx] + sigmoidf_(ig) * tanhf(gg);
  Aoutb[(size_t)b * 768 + j] = (unsigned short)f2bf(sigmoidf_(og) * tanhf(c));
}

// ---------------- the fused NTM head loop: one block per batch row b.
// LDS-resident bf16 memory image; params, scores, softmax/shift/sharpen,
// reads, and in-place updates all inside the block. Writes reads (bf16)
// directly into Aoutb[:, 512:768].
__global__ __launch_bounds__(1024, 4) void k_mega(const float* __restrict__ mem0,
                                                  const float* __restrict__ P,
                                                  const float* __restrict__ prev_w_r,
                                                  const float* __restrict__ prev_w_w,
                                                  unsigned short* __restrict__ Aoutb) {
  const int b = blockIdx.x;
  const int t = threadIdx.x;
  const int l = t & 63;
  const int w = t >> 6;        // wave 0..15
  const int lr = l & 15;       // col-chunk within row
  const int rg = l >> 4;       // row-in-group 0..3
  const int c0 = lr * 4;       // first of 4 columns handled by this lane

  __shared__ unsigned short smem[65536];       // 1024 x 64 bf16 memory image (128 KB)
  __shared__ float Ar[1024], Aw[1024];         // score -> wg -> w buffers per key type
  __shared__ float racc[16][64];               // per-wave read partials
  __shared__ float redA[16], redB[16], redC[16];
  __shared__ float knb[8][64];                 // normalized keys: [type*4+head][col]
  __shared__ float parb[8][8];                 // beta,g,sh0,sh1,sh2,gamma
  __shared__ float eb[4][64], ab[4][64];       // erase/add per write head

  // ---- params phase (waves 0..7: unit = type*4+head)
  if (w < 8) {
    const int type = w >> 2, head = w & 3;
    const float* p = P + (size_t)b * 1072 + (type == 0 ? head * 70 : 280 + head * 198);
    const float kv = tanhf(p[l]);
    float ss = kv * kv;
#pragma unroll
    for (int off = 32; off > 0; off >>= 1) ss += __shfl_xor(ss, off);
    knb[w][l] = kv / (sqrtf(ss) + EPS_);
    if (l == 0) {
      parb[w][0] = softplusf_(p[64]);
      parb[w][1] = sigmoidf_(p[65]);
      const float s0 = p[66], s1 = p[67], s2 = p[68];
      const float mx = fmaxf(s0, fmaxf(s1, s2));
      const float e0 = expf(s0 - mx), e1 = expf(s1 - mx), e2 = expf(s2 - mx);
      const float inv = 1.f / (e0 + e1 + e2);
      parb[w][2] = e0 * inv; parb[w][3] = e1 * inv; parb[w][4] = e2 * inv;
      parb[w][5] = 1.f + softplusf_(p[69]);
    }
    if (type == 1) {
      eb[head][l] = sigmoidf_(p[70 + l]);
      ab[head][l] = tanhf(p[134 + l]);
    }
  }
  __syncthreads();

  // ---- staging (f32 -> bf16 LDS) fused with head-0 scores
  {
    float kr[4], kw[4];
    *(f32x4*)kr = *(const f32x4*)&knb[0][c0];
    *(f32x4*)kw = *(const f32x4*)&knb[4][c0];
    const float4* src = (const float4*)(mem0 + (size_t)b * 65536);
#pragma unroll 4
    for (int k = 0; k < 16; ++k) {
      const int v = k * 1024 + t;      // float4 index; n = v>>4, chunk = v&15 == lr
      const float4 f = src[v];
      const int n = v >> 4;
      uint2 pk;
      pk.x = f2bf(f.x) | (f2bf(f.y) << 16);
      pk.y = f2bf(f.z) | (f2bf(f.w) << 16);
      *(uint2*)&smem[n * 64 + c0] = pk;
      const float v0 = bflo2f(pk.x), v1 = bfhi2f(pk.x);
      const float v2 = bflo2f(pk.y), v3 = bfhi2f(pk.y);
      float ssq = v0 * v0 + v1 * v1 + v2 * v2 + v3 * v3;
      float dr = v0 * kr[0] + v1 * kr[1] + v2 * kr[2] + v3 * kr[3];
      float dw = v0 * kw[0] + v1 * kw[1] + v2 * kw[2] + v3 * kw[3];
#pragma unroll
      for (int off = 1; off < 16; off <<= 1) {
        ssq += __shfl_xor(ssq, off);
        dr += __shfl_xor(dr, off);
        dw += __shfl_xor(dw, off);
      }
      if (lr == 0) {
        const float inv = 1.f / (sqrtf(ssq) + EPS_);
        Ar[n] = dr * inv;
        Aw[n] = dw * inv;
      }
    }
  }

  // ---- head loop
  const int h = w >> 3;          // half 0: read-key, half 1: write-key
  const int u = t & 511;
  float* Abuf = h ? Aw : Ar;

  for (int i = 0; i < 4; ++i) {
    __syncthreads();  // scores visible (staging for i=0; sweep for i>0)

    // finalize: softmax + gate + shift + sharpen (each half handles one key type)
    const float beta = parb[h * 4 + i][0], g = parb[h * 4 + i][1];
    const float sh0 = parb[h * 4 + i][2], sh1 = parb[h * 4 + i][3], sh2 = parb[h * 4 + i][4];
    const float gamma = parb[h * 4 + i][5];
    const float* prevw = (h ? prev_w_w : prev_w_r) + ((size_t)i * 512 + b) * 1024;

    const float z0 = beta * Abuf[u];
    const float z1 = beta * Abuf[u + 512];
    float mx = fmaxf(z0, z1);
#pragma unroll
    for (int off = 32; off > 0; off >>= 1) mx = fmaxf(mx, __shfl_xor(mx, off));
    if (l == 0) redA[w] = mx;
    __syncthreads();
    float gmax = redA[h * 8];
#pragma unroll
    for (int j = 1; j < 8; ++j) gmax = fmaxf(gmax, redA[h * 8 + j]);
    const float e0 = __expf(z0 - gmax), e1 = __expf(z1 - gmax);
    float sm = e0 + e1;
#pragma unroll
    for (int off = 32; off > 0; off >>= 1) sm += __shfl_xor(sm, off);
    if (l == 0) redB[w] = sm;
    __syncthreads();
    float gsum = 0.f;
#pragma unroll
    for (int j = 0; j < 8; ++j) gsum += redB[h * 8 + j];
    const float invs = 1.f / gsum;
    const float wg0 = g * (e0 * invs) + (1.f - g) * prevw[u];
    const float wg1 = g * (e1 * invs) + (1.f - g) * prevw[u + 512];
    Abuf[u] = wg0; Abuf[u + 512] = wg1;
    __syncthreads();
    const float ws0 = sh0 * Abuf[(u + 1023) & 1023] + sh1 * wg0 + sh2 * Abuf[(u + 1) & 1023];
    const float ws1 = sh0 * Abuf[(u + 511) & 1023] + sh1 * wg1 + sh2 * Abuf[(u + 513) & 1023];
    float wp0 = (ws0 > 0.f) ? exp2f(gamma * __log2f(ws0)) : 0.f;
    float wp1 = (ws1 > 0.f) ? exp2f(gamma * __log2f(ws1)) : 0.f;
    float sm2 = wp0 + wp1;
#pragma unroll
    for (int off = 32; off > 0; off >>= 1) sm2 += __shfl_xor(sm2, off);
    if (l == 0) redC[w] = sm2;
    __syncthreads();
    float gsum2 = 0.f;
#pragma unroll
    for (int j = 0; j < 8; ++j) gsum2 += redC[h * 8 + j];
    const float inv2 = 1.f / (gsum2 + EPS_);
    Abuf[u] = wp0 * inv2; Abuf[u + 512] = wp1 * inv2;
    __syncthreads();  // final weights visible

    // combined sweep: read-accum (w_r) + in-place update (w_w) + next-head scores
    float er[4], aa[4], krn[4], kwn[4];
    if (i < 3) {
      *(f32x4*)er = *(const f32x4*)&eb[i][c0];
      *(f32x4*)aa = *(const f32x4*)&ab[i][c0];
      *(f32x4*)krn = *(const f32x4*)&knb[i + 1][c0];
      *(f32x4*)kwn = *(const f32x4*)&knb[5 + i][c0];
    }
    float rl[4] = {0.f, 0.f, 0.f, 0.f};
#pragma unroll 2
    for (int it = 0; it < 16; ++it) {
      const int n = it * 64 + w * 4 + rg;
      uint2 pk = *(uint2*)&smem[n * 64 + c0];
      float v0 = bflo2f(pk.x), v1 = bfhi2f(pk.x);
      float v2 = bflo2f(pk.y), v3 = bfhi2f(pk.y);
      const float wr = Ar[n];
      rl[0] = fmaf(wr, v0, rl[0]); rl[1] = fmaf(wr, v1, rl[1]);
      rl[2] = fmaf(wr, v2, rl[2]); rl[3] = fmaf(wr, v3, rl[3]);
      if (i < 3) {
        const float ww = Aw[n];
        v0 = v0 * (1.f - ww * er[0]) + ww * aa[0];
        v1 = v1 * (1.f - ww * er[1]) + ww * aa[1];
        v2 = v2 * (1.f - ww * er[2]) + ww * aa[2];
        v3 = v3 * (1.f - ww * er[3]) + ww * aa[3];
        pk.x = f2bf(v0) | (f2bf(v1) << 16);
        pk.y = f2bf(v2) | (f2bf(v3) << 16);
        *(uint2*)&smem[n * 64 + c0] = pk;
        const float q0 = bflo2f(pk.x), q1 = bfhi2f(pk.x);
        const float q2 = bflo2f(pk.y), q3 = bfhi2f(pk.y);
        float ssq = q0 * q0 + q1 * q1 + q2 * q2 + q3 * q3;
        float dr = q0 * krn[0] + q1 * krn[1] + q2 * krn[2] + q3 * krn[3];
        float dw = q0 * kwn[0] + q1 * kwn[1] + q2 * kwn[2] + q3 * kwn[3];
#pragma unroll
        for (int off = 1; off < 16; off <<= 1) {
          ssq += __shfl_xor(ssq, off);
          dr += __shfl_xor(dr, off);
          dw += __shfl_xor(dw, off);
        }
        if (lr == 0) {
          const float inv = 1.f / (sqrtf(ssq) + EPS_);
          Ar[n] = dr * inv;   // safe: only this 16-lane group touches row n,
          Aw[n] = dw * inv;   // and its reads of Ar/Aw[n] precede this in program order
        }
      }
    }
    // reduce read partials across row-groups then waves
#pragma unroll
    for (int c = 0; c < 4; ++c) { rl[c] += __shfl_xor(rl[c], 16); rl[c] += __shfl_xor(rl[c], 32); }
    if (rg == 0) *(f32x4*)&racc[w][c0] = *(f32x4*)rl;
    __syncthreads();
    if (t < 64) {
      float s = 0.f;
#pragma unroll
      for (int wv = 0; wv < 16; ++wv) s += racc[wv][t];
      Aoutb[(size_t)b * 768 + 512 + i * 64 + t] = (unsigned short)f2bf(s);
    }
  }
}

extern "C" void kernel_launch(void* const* d_in, const int* in_sizes, int n_in,
                              void* d_out, int out_size, void* d_ws, size_t ws_size,
                              hipStream_t stream) {
  (void)in_sizes; (void)n_in; (void)out_size; (void)ws_size;
  const float* in_data = (const float*)d_in[0];
  const float* memory = (const float*)d_in[1];
  const float* prev_reads = (const float*)d_in[2];
  const float* prev_w_r = (const float*)d_in[3];
  const float* prev_w_w = (const float*)d_in[4];
  const float* h0 = (const float*)d_in[5];
  const float* c0 = (const float*)d_in[6];
  const float* W_ih = (const float*)d_in[7];
  const float* b_ih = (const float*)d_in[8];
  const float* W_hh = (const float*)d_in[9];
  const float* b_hh = (const float*)d_in[10];
  const float* W_rh = (const float*)d_in[11];
  const float* b_rh = (const float*)d_in[12];
  const float* W_wh = (const float*)d_in[13];
  const float* b_wh = (const float*)d_in[14];
  const float* W_out = (const float*)d_in[15];
  const float* b_out = (const float*)d_in[16];
  float* out = (float*)d_out;

  char* base = (char*)d_ws;
  auto alloc = [&](size_t bytes) -> char* {
    char* p = base; base += (bytes + 255) & ~(size_t)255; return p;
  };
  unsigned short* x2b   = (unsigned short*)alloc((size_t)512 * 1024 * 2);
  unsigned short* Wcatb = (unsigned short*)alloc((size_t)2048 * 1024 * 2);
  float* bcat           = (float*)alloc(2048 * 4);
  float* gates          = (float*)alloc((size_t)512 * 2048 * 4);
  unsigned short* W2b   = (unsigned short*)alloc((size_t)1072 * 512 * 2);
  float* bcat2          = (float*)alloc(1072 * 4);
  unsigned short* Woutb = (unsigned short*)alloc((size_t)256 * 768 * 2);
  float* P              = (float*)alloc((size_t)512 * 1072 * 4);
  unsigned short* Aoutb = (unsigned short*)alloc((size_t)512 * 768 * 2);

  k_prep<<<2048, 256, 0, stream>>>(in_data, prev_reads, h0, W_ih, W_hh, b_ih, b_hh,
                                   W_rh, W_wh, W_out, b_rh, b_wh,
                                   x2b, Wcatb, bcat, W2b, Woutb, bcat2);
  k_gemm_mfma<false><<<dim3(64, 16), 64, 0, stream>>>(x2b, 1024, Wcatb, bcat, gates, 2048, 1024, 2048);
  k_lstm<<<1024, 256, 0, stream>>>(gates, c0, Aoutb);
  k_gemm_mfma<false><<<dim3(34, 16), 64, 0, stream>>>(Aoutb, 768, W2b, bcat2, P, 1072, 512, 1072);
  k_mega<<<512, 1024, 0, stream>>>(memory, P, prev_w_r, prev_w_w, Aoutb);
  k_gemm_mfma<true><<<dim3(8, 16), 64, 0, stream>>>(Aoutb, 768, Woutb, b_out, out, 256, 768, 256);
}

// Round 6
// 132.348 us; speedup vs baseline: 4.3417x; 1.3566x over previous
//
#include <hip/hip_runtime.h>
#include <cmath>

#define B_ 512
#define EPS_ 1e-8f

typedef __bf16 bf16x8 __attribute__((ext_vector_type(8)));
typedef float f32x4 __attribute__((ext_vector_type(4)));

__device__ __forceinline__ float sigmoidf_(float x) { return 1.f / (1.f + expf(-x)); }
__device__ __forceinline__ float softplusf_(float x) { return x > 20.f ? x : log1pf(expf(x)); }
__device__ __forceinline__ unsigned f2bf(float x) {
  union { float f; unsigned u; } v; v.f = x;
  unsigned r = v.u + 0x7FFF + ((v.u >> 16) & 1);
  return r >> 16;
}
__device__ __forceinline__ float bfhi2f(unsigned u) { return __uint_as_float(u & 0xffff0000u); }
__device__ __forceinline__ float bflo2f(unsigned u) { return __uint_as_float(u << 16); }

// ---------------- one prep kernel: x2b + all weight conversions (grid-stride)
__global__ void k_prep(const float* __restrict__ in_data, const float* __restrict__ prev_reads,
                       const float* __restrict__ h0,
                       const float* __restrict__ W_ih, const float* __restrict__ W_hh,
                       const float* __restrict__ b_ih, const float* __restrict__ b_hh,
                       const float* __restrict__ W_rh, const float* __restrict__ W_wh,
                       const float* __restrict__ W_out,
                       const float* __restrict__ b_rh, const float* __restrict__ b_wh,
                       unsigned short* __restrict__ x2b,
                       unsigned short* __restrict__ Wcatb, float* __restrict__ bcat,
                       unsigned short* __restrict__ W2b, unsigned short* __restrict__ Woutb,
                       float* __restrict__ bcat2) {
  const int stride = gridDim.x * blockDim.x;
  const int t0 = blockIdx.x * blockDim.x + threadIdx.x;
  for (int i = t0; i < 512 * 1024; i += stride) {
    const int b = i >> 10, j = i & 1023;
    float v;
    if (j < 256) v = in_data[(size_t)b * 256 + j];
    else if (j < 512) { const int jj = j - 256; v = prev_reads[(size_t)(jj >> 6) * B_ * 64 + (size_t)b * 64 + (jj & 63)]; }
    else v = h0[(size_t)b * 512 + (j - 512)];
    x2b[i] = (unsigned short)f2bf(v);
  }
  for (int i = t0; i < 2048 * 1024; i += stride) {
    const int j = i >> 10, k = i & 1023;
    Wcatb[i] = (unsigned short)f2bf(k < 512 ? W_ih[(size_t)j * 512 + k] : W_hh[(size_t)j * 512 + (k - 512)]);
  }
  for (int i = t0; i < 2048; i += stride) bcat[i] = b_ih[i] + b_hh[i];
  for (int i = t0; i < 143360; i += stride) W2b[i] = (unsigned short)f2bf(W_rh[i]);
  for (int i = t0; i < 405504; i += stride) W2b[143360 + i] = (unsigned short)f2bf(W_wh[i]);
  for (int i = t0; i < 196608; i += stride) Woutb[i] = (unsigned short)f2bf(W_out[i]);
  for (int i = t0; i < 280; i += stride) bcat2[i] = b_rh[i];
  for (int i = t0; i < 792; i += stride) bcat2[280 + i] = b_wh[i];
}

// ---------------- bf16 MFMA GEMM, one wave per 32x32 tile, direct-from-global frags
template <bool SIG>
__global__ __launch_bounds__(64) void k_gemm_mfma(const unsigned short* __restrict__ A, int lda,
                                                  const unsigned short* __restrict__ W,
                                                  const float* __restrict__ bias,
                                                  float* __restrict__ C,
                                                  int Nn, int Kk, int ldc) {
  const int l = threadIdx.x;
  const int m0 = blockIdx.y * 32, n0 = blockIdx.x * 32;
  const int lr = l & 15, lk = (l >> 4) * 8;
  f32x4 acc00 = {0.f, 0.f, 0.f, 0.f}, acc01 = acc00, acc10 = acc00, acc11 = acc00;
  const size_t pa0 = (size_t)(m0 + lr) * lda + lk;
  const size_t pa1 = pa0 + (size_t)16 * lda;
  const bool bok0 = (n0 + lr) < Nn, bok1 = (n0 + 16 + lr) < Nn;
  const size_t pb0 = (size_t)(n0 + lr) * Kk + lk;
  const size_t pb1 = pb0 + (size_t)16 * Kk;
#pragma unroll 4
  for (int k0 = 0; k0 < Kk; k0 += 32) {
    bf16x8 a0 = *(const bf16x8*)(A + pa0 + k0);
    bf16x8 a1 = *(const bf16x8*)(A + pa1 + k0);
    bf16x8 b0 = {}, b1 = {};
    if (bok0) b0 = *(const bf16x8*)(W + pb0 + k0);
    if (bok1) b1 = *(const bf16x8*)(W + pb1 + k0);
    acc00 = __builtin_amdgcn_mfma_f32_16x16x32_bf16(a0, b0, acc00, 0, 0, 0);
    acc01 = __builtin_amdgcn_mfma_f32_16x16x32_bf16(a0, b1, acc01, 0, 0, 0);
    acc10 = __builtin_amdgcn_mfma_f32_16x16x32_bf16(a1, b0, acc10, 0, 0, 0);
    acc11 = __builtin_amdgcn_mfma_f32_16x16x32_bf16(a1, b1, acc11, 0, 0, 0);
  }
  const int orow = (l >> 4) * 4;
  f32x4 accs[2][2] = {{acc00, acc01}, {acc10, acc11}};
#pragma unroll
  for (int mi = 0; mi < 2; ++mi) {
#pragma unroll
    for (int nj = 0; nj < 2; ++nj) {
      const int n = n0 + nj * 16 + lr;
      if (n < Nn) {
        const float bv = bias[n];
#pragma unroll
        for (int r = 0; r < 4; ++r) {
          const int m = m0 + mi * 16 + orow + r;
          float v = accs[mi][nj][r] + bv;
          if (SIG) v = 1.f / (1.f + expf(-v));
          C[(size_t)m * ldc + n] = v;
        }
      }
    }
  }
}

// ---------------- LSTM pointwise -> h (bf16) into Aoutb rows (stride 768)
__global__ void k_lstm(const float* __restrict__ gates, const float* __restrict__ c0,
                       unsigned short* __restrict__ Aoutb) {
  const int idx = blockIdx.x * blockDim.x + threadIdx.x;  // < 512*512
  const int b = idx >> 9, j = idx & 511;
  const float* g = gates + (size_t)b * 2048;
  const float ig = g[j], fg = g[512 + j], gg = g[1024 + j], og = g[1536 + j];
  const float c = sigmoidf_(fg) * c0[idx] + sigmoidf_(ig) * tanhf(gg);
  Aoutb[(size_t)b * 768 + j] = (unsigned short)f2bf(sigmoidf_(og) * tanhf(c));
}

// ---------------- fused NTM head loop, one block per batch row.
// LDS bf16 memory image (XOR-swizzled rows); scores & row-norms via MFMA
// (keys as B-operand columns, Gram diagonal for ||mem||^2); softmax/shift/
// sharpen and elementwise update in VALU; reads accumulate per-lane.
__global__ __launch_bounds__(1024, 4) void k_mega(const float* __restrict__ mem0,
                                                  const float* __restrict__ P,
                                                  const float* __restrict__ prev_w_r,
                                                  const float* __restrict__ prev_w_w,
                                                  unsigned short* __restrict__ Aoutb) {
  const int b = blockIdx.x;
  const int t = threadIdx.x;
  const int l = t & 63;
  const int w = t >> 6;        // wave 0..15
  const int lr = l & 15;       // chunk (8B) within row
  const int rg = l >> 4;       // row-in-group 0..3
  const int c0 = lr * 4;       // first of 4 columns handled by this lane

  __shared__ unsigned short smem[65536];       // 1024 x 64 bf16, rows XOR-swizzled (128 KB)
  __shared__ float Ar[1024], Aw[1024];         // raw scores -> weights
  __shared__ float nrm_s[1024];                // ||row||^2 (Gram diag)
  __shared__ float racc[16][64];               // per-wave read partials
  __shared__ float redA[16], redB[16], redC[16];
  __shared__ float knb[8][64];                 // normalized keys [type*4+head][col]
  __shared__ float parb[8][8];                 // beta,g,sh0,sh1,sh2,gamma
  __shared__ float eb[4][64], ab[4][64];       // erase/add per write head

  // ---- params phase (waves 0..7: unit = type*4+head)
  if (w < 8) {
    const int type = w >> 2, head = w & 3;
    const float* p = P + (size_t)b * 1072 + (type == 0 ? head * 70 : 280 + head * 198);
    const float kv = tanhf(p[l]);
    float ss = kv * kv;
#pragma unroll
    for (int off = 32; off > 0; off >>= 1) ss += __shfl_xor(ss, off);
    knb[w][l] = kv / (sqrtf(ss) + EPS_);
    if (l == 0) {
      parb[w][0] = softplusf_(p[64]);
      parb[w][1] = sigmoidf_(p[65]);
      const float s0 = p[66], s1 = p[67], s2 = p[68];
      const float mx = fmaxf(s0, fmaxf(s1, s2));
      const float e0 = expf(s0 - mx), e1 = expf(s1 - mx), e2 = expf(s2 - mx);
      const float inv = 1.f / (e0 + e1 + e2);
      parb[w][2] = e0 * inv; parb[w][3] = e1 * inv; parb[w][4] = e2 * inv;
      parb[w][5] = 1.f + softplusf_(p[69]);
    }
    if (type == 1) {
      eb[head][l] = sigmoidf_(p[70 + l]);
      ab[head][l] = tanhf(p[134 + l]);
    }
  }
  __syncthreads();

  // ---- build key B-fragments in registers (cols 0..3 = read keys, 4..7 = write keys)
  bf16x8 kb0 = {}, kb1 = {};
  {
    const int c = l & 15, ks = (l >> 4) * 8;
    if (c < 8) {
#pragma unroll
      for (int j = 0; j < 8; ++j) {
        kb0[j] = (__bf16)knb[c][ks + j];
        kb1[j] = (__bf16)knb[c][32 + ks + j];
      }
    }
  }

  // ---- staging: f32 memory -> bf16 LDS, swizzled
  {
    const float4* src = (const float4*)(mem0 + (size_t)b * 65536);
#pragma unroll 4
    for (int k = 0; k < 16; ++k) {
      const int v = k * 1024 + t;      // float4 index; n = v>>4, chunk = v&15
      const float4 f = src[v];
      const int n = v >> 4, ch = v & 15;
      uint2 pk;
      pk.x = f2bf(f.x) | (f2bf(f.y) << 16);
      pk.y = f2bf(f.z) | (f2bf(f.w) << 16);
      *(uint2*)((char*)smem + n * 128 + (((ch >> 1) ^ (n & 7)) << 4) + ((ch & 1) << 3)) = pk;
    }
  }

  // ---- MFMA score pass: raw scores for head hj (cols hj, 4+hj) + Gram-diag norms
  auto score_pass = [&](int hj) {
#pragma unroll
    for (int tt = 0; tt < 4; ++tt) {
      const int tile = w * 4 + tt;
      const int row = tile * 16 + (l & 15);
      const int s0 = l >> 4;
      const bf16x8 a0 = *(const bf16x8*)((char*)smem + row * 128 + ((s0 ^ (row & 7)) << 4));
      const bf16x8 a1 = *(const bf16x8*)((char*)smem + row * 128 + (((s0 + 4) ^ (row & 7)) << 4));
      f32x4 sacc = {0.f, 0.f, 0.f, 0.f}, gacc = {0.f, 0.f, 0.f, 0.f};
      sacc = __builtin_amdgcn_mfma_f32_16x16x32_bf16(a0, kb0, sacc, 0, 0, 0);
      sacc = __builtin_amdgcn_mfma_f32_16x16x32_bf16(a1, kb1, sacc, 0, 0, 0);
      gacc = __builtin_amdgcn_mfma_f32_16x16x32_bf16(a0, a0, gacc, 0, 0, 0);
      gacc = __builtin_amdgcn_mfma_f32_16x16x32_bf16(a1, a1, gacc, 0, 0, 0);
      const int c = l & 15, gq = l >> 4;
      if (c == hj)     *(f32x4*)&Ar[tile * 16 + gq * 4] = sacc;
      if (c == 4 + hj) *(f32x4*)&Aw[tile * 16 + gq * 4] = sacc;
      if ((c >> 2) == gq) nrm_s[tile * 16 + c] = gacc[c & 3];
    }
  };

  __syncthreads();
  score_pass(0);

  // ---- head loop
  const int h = w >> 3;          // half 0: read-key, half 1: write-key
  const int u = t & 511;
  float* Abuf = h ? Aw : Ar;

  for (int i = 0; i < 4; ++i) {
    __syncthreads();  // scores + norms visible

    // finalize: cosine-normalize + softmax + gate + shift + sharpen
    const float beta = parb[h * 4 + i][0], g = parb[h * 4 + i][1];
    const float sh0 = parb[h * 4 + i][2], sh1 = parb[h * 4 + i][3], sh2 = parb[h * 4 + i][4];
    const float gamma = parb[h * 4 + i][5];
    const float* prevw = (h ? prev_w_w : prev_w_r) + ((size_t)i * 512 + b) * 1024;

    const float z0 = beta * Abuf[u] / (sqrtf(nrm_s[u]) + EPS_);
    const float z1 = beta * Abuf[u + 512] / (sqrtf(nrm_s[u + 512]) + EPS_);
    float mx = fmaxf(z0, z1);
#pragma unroll
    for (int off = 32; off > 0; off >>= 1) mx = fmaxf(mx, __shfl_xor(mx, off));
    if (l == 0) redA[w] = mx;
    __syncthreads();
    float gmax = redA[h * 8];
#pragma unroll
    for (int j = 1; j < 8; ++j) gmax = fmaxf(gmax, redA[h * 8 + j]);
    const float e0 = __expf(z0 - gmax), e1 = __expf(z1 - gmax);
    float sm = e0 + e1;
#pragma unroll
    for (int off = 32; off > 0; off >>= 1) sm += __shfl_xor(sm, off);
    if (l == 0) redB[w] = sm;
    __syncthreads();
    float gsum = 0.f;
#pragma unroll
    for (int j = 0; j < 8; ++j) gsum += redB[h * 8 + j];
    const float invs = 1.f / gsum;
    const float wg0 = g * (e0 * invs) + (1.f - g) * prevw[u];
    const float wg1 = g * (e1 * invs) + (1.f - g) * prevw[u + 512];
    Abuf[u] = wg0; Abuf[u + 512] = wg1;
    __syncthreads();
    const float ws0 = sh0 * Abuf[(u + 1023) & 1023] + sh1 * wg0 + sh2 * Abuf[(u + 1) & 1023];
    const float ws1 = sh0 * Abuf[(u + 511) & 1023] + sh1 * wg1 + sh2 * Abuf[(u + 513) & 1023];
    float wp0 = (ws0 > 0.f) ? exp2f(gamma * __log2f(ws0)) : 0.f;
    float wp1 = (ws1 > 0.f) ? exp2f(gamma * __log2f(ws1)) : 0.f;
    float sm2 = wp0 + wp1;
#pragma unroll
    for (int off = 32; off > 0; off >>= 1) sm2 += __shfl_xor(sm2, off);
    if (l == 0) redC[w] = sm2;
    __syncthreads();
    float gsum2 = 0.f;
#pragma unroll
    for (int j = 0; j < 8; ++j) gsum2 += redC[h * 8 + j];
    const float inv2 = 1.f / (gsum2 + EPS_);
    Abuf[u] = wp0 * inv2; Abuf[u + 512] = wp1 * inv2;
    __syncthreads();  // final weights visible

    // sweep: read-accum (Ar) + in-place update (Aw) — no per-iteration reductions
    float er[4], aa[4];
    if (i < 3) {
      *(f32x4*)er = *(const f32x4*)&eb[i][c0];
      *(f32x4*)aa = *(const f32x4*)&ab[i][c0];
    }
    float rl[4] = {0.f, 0.f, 0.f, 0.f};
#pragma unroll 2
    for (int it = 0; it < 16; ++it) {
      const int n = it * 64 + w * 4 + rg;
      char* p = (char*)smem + n * 128 + (((lr >> 1) ^ (n & 7)) << 4) + ((lr & 1) << 3);
      uint2 pk = *(uint2*)p;
      float v0 = bflo2f(pk.x), v1 = bfhi2f(pk.x);
      float v2 = bflo2f(pk.y), v3 = bfhi2f(pk.y);
      const float wr = Ar[n];
      rl[0] = fmaf(wr, v0, rl[0]); rl[1] = fmaf(wr, v1, rl[1]);
      rl[2] = fmaf(wr, v2, rl[2]); rl[3] = fmaf(wr, v3, rl[3]);
      if (i < 3) {
        const float ww = Aw[n];
        v0 = v0 * (1.f - ww * er[0]) + ww * aa[0];
        v1 = v1 * (1.f - ww * er[1]) + ww * aa[1];
        v2 = v2 * (1.f - ww * er[2]) + ww * aa[2];
        v3 = v3 * (1.f - ww * er[3]) + ww * aa[3];
        pk.x = f2bf(v0) | (f2bf(v1) << 16);
        pk.y = f2bf(v2) | (f2bf(v3) << 16);
        *(uint2*)p = pk;
      }
    }
#pragma unroll
    for (int c = 0; c < 4; ++c) { rl[c] += __shfl_xor(rl[c], 16); rl[c] += __shfl_xor(rl[c], 32); }
    if (rg == 0) *(f32x4*)&racc[w][c0] = *(f32x4*)rl;
    __syncthreads();  // smem updated + racc complete
    if (i < 3) score_pass(i + 1);
    if (t < 64) {
      float s = 0.f;
#pragma unroll
      for (int wv = 0; wv < 16; ++wv) s += racc[wv][t];
      Aoutb[(size_t)b * 768 + 512 + i * 64 + t] = (unsigned short)f2bf(s);
    }
  }
}

extern "C" void kernel_launch(void* const* d_in, const int* in_sizes, int n_in,
                              void* d_out, int out_size, void* d_ws, size_t ws_size,
                              hipStream_t stream) {
  (void)in_sizes; (void)n_in; (void)out_size; (void)ws_size;
  const float* in_data = (const float*)d_in[0];
  const float* memory = (const float*)d_in[1];
  const float* prev_reads = (const float*)d_in[2];
  const float* prev_w_r = (const float*)d_in[3];
  const float* prev_w_w = (const float*)d_in[4];
  const float* h0 = (const float*)d_in[5];
  const float* c0 = (const float*)d_in[6];
  const float* W_ih = (const float*)d_in[7];
  const float* b_ih = (const float*)d_in[8];
  const float* W_hh = (const float*)d_in[9];
  const float* b_hh = (const float*)d_in[10];
  const float* W_rh = (const float*)d_in[11];
  const float* b_rh = (const float*)d_in[12];
  const float* W_wh = (const float*)d_in[13];
  const float* b_wh = (const float*)d_in[14];
  const float* W_out = (const float*)d_in[15];
  const float* b_out = (const float*)d_in[16];
  float* out = (float*)d_out;

  char* base = (char*)d_ws;
  auto alloc = [&](size_t bytes) -> char* {
    char* p = base; base += (bytes + 255) & ~(size_t)255; return p;
  };
  unsigned short* x2b   = (unsigned short*)alloc((size_t)512 * 1024 * 2);
  unsigned short* Wcatb = (unsigned short*)alloc((size_t)2048 * 1024 * 2);
  float* bcat           = (float*)alloc(2048 * 4);
  float* gates          = (float*)alloc((size_t)512 * 2048 * 4);
  unsigned short* W2b   = (unsigned short*)alloc((size_t)1072 * 512 * 2);
  float* bcat2          = (float*)alloc(1072 * 4);
  unsigned short* Woutb = (unsigned short*)alloc((size_t)256 * 768 * 2);
  float* P              = (float*)alloc((size_t)512 * 1072 * 4);
  unsigned short* Aoutb = (unsigned short*)alloc((size_t)512 * 768 * 2);

  k_prep<<<2048, 256, 0, stream>>>(in_data, prev_reads, h0, W_ih, W_hh, b_ih, b_hh,
                                   W_rh, W_wh, W_out, b_rh, b_wh,
                                   x2b, Wcatb, bcat, W2b, Woutb, bcat2);
  k_gemm_mfma<false><<<dim3(64, 16), 64, 0, stream>>>(x2b, 1024, Wcatb, bcat, gates, 2048, 1024, 2048);
  k_lstm<<<1024, 256, 0, stream>>>(gates, c0, Aoutb);
  k_gemm_mfma<false><<<dim3(34, 16), 64, 0, stream>>>(Aoutb, 768, W2b, bcat2, P, 1072, 512, 1072);
  k_mega<<<512, 1024, 0, stream>>>(memory, P, prev_w_r, prev_w_w, Aoutb);
  k_gemm_mfma<true><<<dim3(8, 16), 64, 0, stream>>>(Aoutb, 768, Woutb, b_out, out, 256, 768, 256);
}